// Round 9
// baseline (426.923 us; speedup 1.0000x reference)
//
#include <hip/hip_runtime.h>
#include <stdint.h>

#define N 8192
#define KSPLIT 8               // K-slabs for k_layer2a
#define BK 64                  // K elems per LDS tile
#define KPB (N / KSPLIT)       // 1024 K per block
#define TILES (KPB / BK)       // 16 tiles per block

// DIAGNOSTIC: distinct REP multipliers surface each kernel above the 155 µs
// fillBuffer floor in rocprof top-5. True cost = dur / REP. Identical work
// and writes each rep -> deterministic, passes re-validation.
#define REP_K1 4
#define REP_K3 12
#define REP_K4 12

typedef __attribute__((ext_vector_type(8))) short sh8;
typedef __attribute__((ext_vector_type(4))) float f32x4;
typedef __attribute__((ext_vector_type(2))) float f32x2;

static __device__ __forceinline__ unsigned short f2bf(float f) {
    union { float f; unsigned u; } v; v.f = f;
    unsigned r = v.u + 0x7FFF + ((v.u >> 16) & 1);   // round-to-nearest-even
    return (unsigned short)(r >> 16);
}

static __device__ __forceinline__ float bflo(unsigned u) {
    union { unsigned u; float f; } v; v.u = u << 16;
    return v.f;
}

static __device__ __forceinline__ float bfhi(unsigned u) {
    union { unsigned u; float f; } v; v.u = u & 0xFFFF0000u;
    return v.f;
}

static __device__ __forceinline__ unsigned fbits(float f) {
    union { float f; unsigned u; } v; v.f = f;
    return v.u;
}

static __device__ __forceinline__ void glds16(const void* g, void* l) {
    __builtin_amdgcn_global_load_lds(
        (const __attribute__((address_space(1))) void*)g,
        (__attribute__((address_space(3))) void*)l, 16, 0, 0);
}

// Pass 1: deg[i] = row-sum of adj (f32); write fp8 e4m3 copy of (adj + I).
// Reduce via wave shuffles + single barrier (was 8-barrier LDS tree).
__global__ __launch_bounds__(256) void k_deg_conv(const float* __restrict__ adj,
        unsigned char* __restrict__ abf, float* __restrict__ deg) {
    int row = blockIdx.x;
    const float* arow = adj + (size_t)row * N;
    unsigned* brow = (unsigned*)(abf + (size_t)row * N);
    int t = threadIdx.x;
    int wave = t >> 6, lane = t & 63;
    __shared__ float red4[4];
    for (int rep = 0; rep < REP_K1; ++rep) {
        float sum = 0.f;
        #pragma unroll
        for (int it = 0; it < N / 1024; ++it) {      // 8 iters of float4 per thread
            int j = (it * 256 + t) * 4;
            float4 v = *(const float4*)(arow + j);
            sum += v.x + v.y + v.z + v.w;
            int d = row - j;                          // diag lands here iff d in [0,4)
            float x0 = v.x + ((d == 0) ? 1.f : 0.f);
            float x1 = v.y + ((d == 1) ? 1.f : 0.f);
            float x2 = v.z + ((d == 2) ? 1.f : 0.f);
            float x3 = v.w + ((d == 3) ? 1.f : 0.f);
            unsigned p = __builtin_amdgcn_cvt_pk_fp8_f32(x0, x1, 0, false);
            p = __builtin_amdgcn_cvt_pk_fp8_f32(x2, x3, p, true);
            brow[it * 256 + t] = p;                   // 4 fp8 per u32, coalesced
        }
        #pragma unroll
        for (int m = 1; m < 64; m <<= 1) sum += __shfl_xor(sum, m);
        if (lane == 0) red4[wave] = sum;
        __syncthreads();
        if (t == 0) deg[row] = red4[0] + red4[1] + red4[2] + red4[3];
        __syncthreads();                              // red4 reuse across reps
        asm volatile("" ::: "memory");
    }
}

// Pass 2 (single block): gmax; s (f32); yb[j] = pack(bf16(y1), bf16(y0)).
__global__ __launch_bounds__(1024) void k_scalars(const float* __restrict__ deg,
        float* __restrict__ s, unsigned* __restrict__ yb) {
    __shared__ float red[1024];
    int t = threadIdx.x;
    float m = 1.0f;
    for (int i = t; i < N; i += 1024) m = fmaxf(m, deg[i]);
    red[t] = m; __syncthreads();
    for (int sz = 512; sz > 0; sz >>= 1) {
        if (t < sz) red[t] = fmaxf(red[t], red[t + sz]);
        __syncthreads();
    }
    float gmax = red[0];
    for (int i = t; i < N; i += 1024) {
        float d = deg[i];
        float si = 1.0f / sqrtf(fmaxf(d + 1.0f, 1.0f));
        s[i] = si;
        unsigned lo = f2bf(si);
        unsigned hi = f2bf(si * (d / gmax));
        yb[i] = (hi << 16) | lo;
    }
}

// Pass 3: one wave per row. z = a_row . [y0, y1] (a fp8, y packed bf16x2);
// h1 = relu(s_i*z@W1 + b1); store gT[c][i] = bf16(s_i * h1[i][c]).
__global__ __launch_bounds__(256) void k_layer1(const unsigned char* __restrict__ abf,
        const unsigned* __restrict__ yb, const float* __restrict__ s,
        const float* __restrict__ W1, const float* __restrict__ b1,
        unsigned short* __restrict__ gT) {
    int wave = threadIdx.x >> 6;
    int lane = threadIdx.x & 63;
    int row = blockIdx.x * 4 + wave;
    const unsigned char* arow = abf + (size_t)row * N;
    for (int rep = 0; rep < REP_K3; ++rep) {
        float z0 = 0.f, z1 = 0.f;
        #pragma unroll 4
        for (int it = 0; it < N / 512; ++it) {   // 16 iters, 8 elems/lane/iter
            int j = it * 512 + lane * 8;
            uint2 a8 = *(const uint2*)(arow + j);
            uint4 w0 = *(const uint4*)(yb + j);
            uint4 w1 = *(const uint4*)(yb + j + 4);
            f32x2 c01 = __builtin_amdgcn_cvt_pk_f32_fp8((int)a8.x, false);
            f32x2 c23 = __builtin_amdgcn_cvt_pk_f32_fp8((int)a8.x, true);
            f32x2 c45 = __builtin_amdgcn_cvt_pk_f32_fp8((int)a8.y, false);
            f32x2 c67 = __builtin_amdgcn_cvt_pk_f32_fp8((int)a8.y, true);
            z0 += c01.x * bflo(w0.x) + c01.y * bflo(w0.y)
                + c23.x * bflo(w0.z) + c23.y * bflo(w0.w)
                + c45.x * bflo(w1.x) + c45.y * bflo(w1.y)
                + c67.x * bflo(w1.z) + c67.y * bflo(w1.w);
            z1 += c01.x * bfhi(w0.x) + c01.y * bfhi(w0.y)
                + c23.x * bfhi(w0.z) + c23.y * bfhi(w0.w)
                + c45.x * bfhi(w1.x) + c45.y * bfhi(w1.y)
                + c67.x * bfhi(w1.z) + c67.y * bfhi(w1.w);
        }
        #pragma unroll
        for (int m = 1; m < 64; m <<= 1) {
            z0 += __shfl_xor(z0, m);
            z1 += __shfl_xor(z1, m);
        }
        float si = s[row];
        float h = si * (z0 * W1[lane] + z1 * W1[64 + lane]) + b1[lane];
        h = fmaxf(h, 0.f);
        gT[(size_t)lane * N + row] = f2bf(si * h);
        asm volatile("" ::: "memory");
    }
}

// Pass 4a: partial t = A @ g over a K-slab. A fp8 in LDS (exact-converted to
// bf16 in regs), g bf16 in LDS; bf16 MFMA 16x16x32.
__global__ __launch_bounds__(256) void k_layer2a(const unsigned char* __restrict__ abf,
        const unsigned short* __restrict__ gT, float* __restrict__ tpart) {
    __shared__ unsigned char  Al[2][64 * 64];    // 4 KB each
    __shared__ unsigned short Bl[2][64 * 64];    // 8 KB each
    int tid = threadIdx.x;
    int wave = tid >> 6, lane = tid & 63;
    int r0 = blockIdx.x * 64;
    int kbase0 = blockIdx.y * KPB;

    int r = lane & 15, q = lane >> 4;

    #define STAGE(buf, kbase)                                                   \
        do {                                                                    \
            {                                                                   \
                int idx = tid;                                                  \
                int srow = idx >> 2, sch = (idx & 3) ^ (srow & 3);              \
                glds16(abf + (size_t)(r0 + srow) * N + (kbase) + sch * 16,      \
                       &Al[buf][idx * 16]);                                     \
            }                                                                   \
            _Pragma("unroll")                                                   \
            for (int i = 0; i < 2; ++i) {                                       \
                int idx = i * 256 + tid;                                        \
                int srow = idx >> 3, sch = (idx & 7) ^ (srow & 7);              \
                glds16(gT + (size_t)srow * N + (kbase) + sch * 8,               \
                       &Bl[buf][idx * 8]);                                      \
            }                                                                   \
        } while (0)

    for (int rep = 0; rep < REP_K4; ++rep) {
        f32x4 acc0 = {0,0,0,0}, acc1 = {0,0,0,0}, acc2 = {0,0,0,0}, acc3 = {0,0,0,0};
        STAGE(0, kbase0);
        __syncthreads();
        for (int t = 0; t < TILES; ++t) {
            int cur = t & 1;
            if (t + 1 < TILES) STAGE(cur ^ 1, kbase0 + (t + 1) * BK);
            int arow = wave * 16 + r;
            #pragma unroll
            for (int ks = 0; ks < 2; ++ks) {            // 2 K-steps of 32 per tile
                int acho = (((ks * 2 + (q >> 1)) ^ (arow & 3)) * 16) + (q & 1) * 8;
                uint2 a8 = *(const uint2*)&Al[cur][arow * 64 + acho];
                f32x2 c01 = __builtin_amdgcn_cvt_pk_f32_fp8((int)a8.x, false);
                f32x2 c23 = __builtin_amdgcn_cvt_pk_f32_fp8((int)a8.x, true);
                f32x2 c45 = __builtin_amdgcn_cvt_pk_f32_fp8((int)a8.y, false);
                f32x2 c67 = __builtin_amdgcn_cvt_pk_f32_fp8((int)a8.y, true);
                union { unsigned u[4]; sh8 v; } af;
                af.u[0] = (fbits(c01.y) & 0xFFFF0000u) | (fbits(c01.x) >> 16);
                af.u[1] = (fbits(c23.y) & 0xFFFF0000u) | (fbits(c23.x) >> 16);
                af.u[2] = (fbits(c45.y) & 0xFFFF0000u) | (fbits(c45.x) >> 16);
                af.u[3] = (fbits(c67.y) & 0xFFFF0000u) | (fbits(c67.x) >> 16);
                int chb = ((ks * 4 + q) ^ (r & 7)) * 8;
                sh8 b0 = *(const sh8*)&Bl[cur][(r     ) * 64 + chb];
                sh8 b1 = *(const sh8*)&Bl[cur][(r + 16) * 64 + chb];
                sh8 b2 = *(const sh8*)&Bl[cur][(r + 32) * 64 + chb];
                sh8 b3 = *(const sh8*)&Bl[cur][(r + 48) * 64 + chb];
                acc0 = __builtin_amdgcn_mfma_f32_16x16x32_bf16(af.v, b0, acc0, 0, 0, 0);
                acc1 = __builtin_amdgcn_mfma_f32_16x16x32_bf16(af.v, b1, acc1, 0, 0, 0);
                acc2 = __builtin_amdgcn_mfma_f32_16x16x32_bf16(af.v, b2, acc2, 0, 0, 0);
                acc3 = __builtin_amdgcn_mfma_f32_16x16x32_bf16(af.v, b3, acc3, 0, 0, 0);
            }
            __syncthreads();   // drains vmcnt(0): next-tile stage has landed
        }
        // C/D layout (m89-verified): col = lane&15, row = (lane>>4)*4 + reg
        float* tp = tpart + (size_t)blockIdx.y * N * 64;
        int growb = r0 + wave * 16 + q * 4;
        #pragma unroll
        for (int rr = 0; rr < 4; ++rr) {
            tp[(size_t)(growb + rr) * 64 + r     ] = acc0[rr];
            tp[(size_t)(growb + rr) * 64 + r + 16] = acc1[rr];
            tp[(size_t)(growb + rr) * 64 + r + 32] = acc2[rr];
            tp[(size_t)(growb + rr) * 64 + r + 48] = acc3[rr];
        }
        asm volatile("" ::: "memory");
    }
    #undef STAGE
}

// Pass 4b: t = sum of KSPLIT partials; out = s .* (t @ W2) + b2.
__global__ __launch_bounds__(256) void k_layer2b(const float* __restrict__ tpart,
        const float* __restrict__ s, const float* __restrict__ W2,
        const float* __restrict__ b2, float* __restrict__ out) {
    __shared__ float ts[4][64];
    int tid = threadIdx.x;
    int r0 = blockIdx.x * 4;
    int rg = tid >> 6, c = tid & 63;
    float v = 0.f;
    #pragma unroll
    for (int kb = 0; kb < KSPLIT; ++kb)
        v += tpart[(size_t)kb * N * 64 + (size_t)(r0 + rg) * 64 + c];
    ts[rg][c] = v;
    __syncthreads();
    float acc = 0.f;
    #pragma unroll 8
    for (int cc = 0; cc < 64; ++cc)
        acc += ts[rg][cc] * W2[cc * 64 + c];
    int row = r0 + rg;
    out[(size_t)row * 64 + c] = s[row] * acc + b2[c];
}

extern "C" void kernel_launch(void* const* d_in, const int* in_sizes, int n_in,
                              void* d_out, int out_size, void* d_ws, size_t ws_size,
                              hipStream_t stream) {
    const float* adj = (const float*)d_in[0];
    const float* W1  = (const float*)d_in[1];
    const float* b1  = (const float*)d_in[2];
    const float* W2  = (const float*)d_in[3];
    const float* b2  = (const float*)d_in[4];
    float* out = (float*)d_out;

    char* ws = (char*)d_ws;
    unsigned char*  abf = (unsigned char*)ws;                               // 64 MB
    unsigned short* gT  = (unsigned short*)(ws + (size_t)N * N);            // 1 MB
    float* tpart = (float*)(ws + (size_t)N * N + (size_t)64 * N * 2);       // 16 MB
    float* deg = tpart + (size_t)KSPLIT * N * 64;
    float* s   = deg + N;
    unsigned* yb = (unsigned*)(s + N);

    hipLaunchKernelGGL(k_deg_conv, dim3(N),      dim3(256),  0, stream, adj, abf, deg);
    hipLaunchKernelGGL(k_scalars,  dim3(1),      dim3(1024), 0, stream, deg, s, yb);
    hipLaunchKernelGGL(k_layer1,   dim3(N / 4),  dim3(256),  0, stream, abf, yb, s, W1, b1, gT);
    hipLaunchKernelGGL(k_layer2a,  dim3(N / 64, KSPLIT), dim3(256), 0, stream, abf, gT, tpart);
    hipLaunchKernelGGL(k_layer2b,  dim3(N / 4),  dim3(256),  0, stream, tpart, s, W2, b2, out);
}

// Round 10
// 254.519 us; speedup vs baseline: 1.6774x; 1.6774x over previous
//
#include <hip/hip_runtime.h>
#include <stdint.h>

#define N 8192
#define KSPLIT 8               // K-slabs for k_layer2
#define BK 64                  // K elems per LDS tile
#define KPB (N / KSPLIT)       // 1024 K per block
#define TILES (KPB / BK)       // 16 tiles per block

typedef __attribute__((ext_vector_type(8))) short sh8;
typedef __attribute__((ext_vector_type(4))) float f32x4;
typedef __attribute__((ext_vector_type(2))) float f32x2;

static __device__ __forceinline__ unsigned short f2bf(float f) {
    union { float f; unsigned u; } v; v.f = f;
    unsigned r = v.u + 0x7FFF + ((v.u >> 16) & 1);   // round-to-nearest-even
    return (unsigned short)(r >> 16);
}

static __device__ __forceinline__ float bflo(unsigned u) {
    union { unsigned u; float f; } v; v.u = u << 16;
    return v.f;
}

static __device__ __forceinline__ float bfhi(unsigned u) {
    union { unsigned u; float f; } v; v.u = u & 0xFFFF0000u;
    return v.f;
}

static __device__ __forceinline__ unsigned fbits(float f) {
    union { float f; unsigned u; } v; v.f = f;
    return v.u;
}

static __device__ __forceinline__ void glds16(const void* g, void* l) {
    __builtin_amdgcn_global_load_lds(
        (const __attribute__((address_space(1))) void*)g,
        (__attribute__((address_space(3))) void*)l, 16, 0, 0);
}

// Pass 1: deg[i] = row-sum of adj (f32); write fp8 e4m3 copy of (adj + I).
// Block 0 also zeroes the k_layer2 rowgroup counters (fresh every launch ->
// replay-deterministic despite no harness re-poison).
__global__ __launch_bounds__(256) void k_deg_conv(const float* __restrict__ adj,
        unsigned char* __restrict__ abf, float* __restrict__ deg,
        unsigned* __restrict__ cnt) {
    int row = blockIdx.x;
    int t = threadIdx.x;
    if (blockIdx.x == 0 && t < 128) cnt[t] = 0;
    const float* arow = adj + (size_t)row * N;
    unsigned* brow = (unsigned*)(abf + (size_t)row * N);
    int wave = t >> 6, lane = t & 63;
    __shared__ float red4[4];
    float sum = 0.f;
    #pragma unroll
    for (int it = 0; it < N / 1024; ++it) {      // 8 iters of float4 per thread
        int j = (it * 256 + t) * 4;
        float4 v = *(const float4*)(arow + j);
        sum += v.x + v.y + v.z + v.w;
        int d = row - j;                          // diag lands here iff d in [0,4)
        float x0 = v.x + ((d == 0) ? 1.f : 0.f);
        float x1 = v.y + ((d == 1) ? 1.f : 0.f);
        float x2 = v.z + ((d == 2) ? 1.f : 0.f);
        float x3 = v.w + ((d == 3) ? 1.f : 0.f);
        unsigned p = __builtin_amdgcn_cvt_pk_fp8_f32(x0, x1, 0, false);
        p = __builtin_amdgcn_cvt_pk_fp8_f32(x2, x3, p, true);
        brow[it * 256 + t] = p;                   // 4 fp8 per u32, coalesced
    }
    #pragma unroll
    for (int m = 1; m < 64; m <<= 1) sum += __shfl_xor(sum, m);
    if (lane == 0) red4[wave] = sum;
    __syncthreads();
    if (t == 0) deg[row] = red4[0] + red4[1] + red4[2] + red4[3];
}

// Pass 2 (fused k2+k3): per block, recompute gmax + packed y in LDS
// (bit-identical across blocks: fmax is order-invariant, same code path),
// then one wave per row: z = a_row . [y0, y1]; h1 = relu(s_i*z@W1 + b1);
// store gT[c][i] = bf16(s_i * h1[i][c]).
__global__ __launch_bounds__(256) void k_layer1(const unsigned char* __restrict__ abf,
        const float* __restrict__ deg, const float* __restrict__ W1,
        const float* __restrict__ b1, unsigned short* __restrict__ gT) {
    __shared__ unsigned ybs[N];                   // 32 KB packed bf16x2 y
    __shared__ float redw[4];
    int tid = threadIdx.x;
    int wave = tid >> 6, lane = tid & 63;
    int row = blockIdx.x * 4 + wave;
    // --- scalars prologue (deg is 32 KB, L2-hot) ---
    float m = 1.0f;
    #pragma unroll
    for (int it = 0; it < N / 1024; ++it) {
        float4 d = *(const float4*)(deg + (it * 256 + tid) * 4);
        m = fmaxf(fmaxf(fmaxf(m, d.x), fmaxf(d.y, d.z)), d.w);
    }
    #pragma unroll
    for (int o = 1; o < 64; o <<= 1) m = fmaxf(m, __shfl_xor(m, o));
    if (lane == 0) redw[wave] = m;
    __syncthreads();
    float gmax = fmaxf(fmaxf(redw[0], redw[1]), fmaxf(redw[2], redw[3]));
    #pragma unroll
    for (int it = 0; it < N / 1024; ++it) {
        int j = (it * 256 + tid) * 4;
        float4 d = *(const float4*)(deg + j);
        float s0 = 1.0f / sqrtf(fmaxf(d.x + 1.0f, 1.0f));
        float s1 = 1.0f / sqrtf(fmaxf(d.y + 1.0f, 1.0f));
        float s2 = 1.0f / sqrtf(fmaxf(d.z + 1.0f, 1.0f));
        float s3 = 1.0f / sqrtf(fmaxf(d.w + 1.0f, 1.0f));
        ybs[j    ] = ((unsigned)f2bf(s0 * (d.x / gmax)) << 16) | f2bf(s0);
        ybs[j + 1] = ((unsigned)f2bf(s1 * (d.y / gmax)) << 16) | f2bf(s1);
        ybs[j + 2] = ((unsigned)f2bf(s2 * (d.z / gmax)) << 16) | f2bf(s2);
        ybs[j + 3] = ((unsigned)f2bf(s3 * (d.w / gmax)) << 16) | f2bf(s3);
    }
    __syncthreads();
    // --- main loop: y from LDS ---
    const unsigned char* arow = abf + (size_t)row * N;
    float z0 = 0.f, z1 = 0.f;
    #pragma unroll 4
    for (int it = 0; it < N / 512; ++it) {   // 16 iters, 8 elems/lane/iter
        int j = it * 512 + lane * 8;
        uint2 a8 = *(const uint2*)(arow + j);
        uint4 w0 = *(const uint4*)&ybs[j];
        uint4 w1 = *(const uint4*)&ybs[j + 4];
        f32x2 c01 = __builtin_amdgcn_cvt_pk_f32_fp8((int)a8.x, false);
        f32x2 c23 = __builtin_amdgcn_cvt_pk_f32_fp8((int)a8.x, true);
        f32x2 c45 = __builtin_amdgcn_cvt_pk_f32_fp8((int)a8.y, false);
        f32x2 c67 = __builtin_amdgcn_cvt_pk_f32_fp8((int)a8.y, true);
        z0 += c01.x * bflo(w0.x) + c01.y * bflo(w0.y)
            + c23.x * bflo(w0.z) + c23.y * bflo(w0.w)
            + c45.x * bflo(w1.x) + c45.y * bflo(w1.y)
            + c67.x * bflo(w1.z) + c67.y * bflo(w1.w);
        z1 += c01.x * bfhi(w0.x) + c01.y * bfhi(w0.y)
            + c23.x * bfhi(w0.z) + c23.y * bfhi(w0.w)
            + c45.x * bfhi(w1.x) + c45.y * bfhi(w1.y)
            + c67.x * bfhi(w1.z) + c67.y * bfhi(w1.w);
    }
    #pragma unroll
    for (int o = 1; o < 64; o <<= 1) {
        z0 += __shfl_xor(z0, o);
        z1 += __shfl_xor(z1, o);
    }
    float dv = deg[row];
    float si = 1.0f / sqrtf(fmaxf(dv + 1.0f, 1.0f));   // exact f32 s_i
    float h = si * (z0 * W1[lane] + z1 * W1[64 + lane]) + b1[lane];
    h = fmaxf(h, 0.f);
    gT[(size_t)lane * N + row] = f2bf(si * h);
}

// Pass 3 (fused k4a+k4b): partial t = A @ g over a K-slab; the last block of
// each rowgroup (threadfence-reduction pattern) sums the KSPLIT slabs in fixed
// order (deterministic) and applies out = s .* (t @ W2) + b2.
__global__ __launch_bounds__(256) void k_layer2(const unsigned char* __restrict__ abf,
        const unsigned short* __restrict__ gT, const float* __restrict__ deg,
        const float* __restrict__ W2, const float* __restrict__ b2,
        float* __restrict__ tpart, unsigned* __restrict__ cnt,
        float* __restrict__ out) {
    __shared__ unsigned char  Al[2][64 * 64];    // 4 KB each
    __shared__ unsigned short Bl[2][64 * 64];    // 8 KB each
    __shared__ unsigned lastf;
    int tid = threadIdx.x;
    int wave = tid >> 6, lane = tid & 63;
    int r0 = blockIdx.x * 64;
    int kbase0 = blockIdx.y * KPB;

    int r = lane & 15, q = lane >> 4;

    f32x4 acc0 = {0,0,0,0}, acc1 = {0,0,0,0}, acc2 = {0,0,0,0}, acc3 = {0,0,0,0};

    #define STAGE(buf, kbase)                                                   \
        do {                                                                    \
            {                                                                   \
                int idx = tid;                                                  \
                int srow = idx >> 2, sch = (idx & 3) ^ (srow & 3);              \
                glds16(abf + (size_t)(r0 + srow) * N + (kbase) + sch * 16,      \
                       &Al[buf][idx * 16]);                                     \
            }                                                                   \
            _Pragma("unroll")                                                   \
            for (int i = 0; i < 2; ++i) {                                       \
                int idx = i * 256 + tid;                                        \
                int srow = idx >> 3, sch = (idx & 7) ^ (srow & 7);              \
                glds16(gT + (size_t)srow * N + (kbase) + sch * 8,               \
                       &Bl[buf][idx * 8]);                                      \
            }                                                                   \
        } while (0)

    STAGE(0, kbase0);
    __syncthreads();

    for (int t = 0; t < TILES; ++t) {
        int cur = t & 1;
        if (t + 1 < TILES) STAGE(cur ^ 1, kbase0 + (t + 1) * BK);
        int arow = wave * 16 + r;
        #pragma unroll
        for (int ks = 0; ks < 2; ++ks) {            // 2 K-steps of 32 per tile
            int acho = (((ks * 2 + (q >> 1)) ^ (arow & 3)) * 16) + (q & 1) * 8;
            uint2 a8 = *(const uint2*)&Al[cur][arow * 64 + acho];
            f32x2 c01 = __builtin_amdgcn_cvt_pk_f32_fp8((int)a8.x, false);
            f32x2 c23 = __builtin_amdgcn_cvt_pk_f32_fp8((int)a8.x, true);
            f32x2 c45 = __builtin_amdgcn_cvt_pk_f32_fp8((int)a8.y, false);
            f32x2 c67 = __builtin_amdgcn_cvt_pk_f32_fp8((int)a8.y, true);
            union { unsigned u[4]; sh8 v; } af;     // fp8 ⊂ bf16: exact repack
            af.u[0] = (fbits(c01.y) & 0xFFFF0000u) | (fbits(c01.x) >> 16);
            af.u[1] = (fbits(c23.y) & 0xFFFF0000u) | (fbits(c23.x) >> 16);
            af.u[2] = (fbits(c45.y) & 0xFFFF0000u) | (fbits(c45.x) >> 16);
            af.u[3] = (fbits(c67.y) & 0xFFFF0000u) | (fbits(c67.x) >> 16);
            int chb = ((ks * 4 + q) ^ (r & 7)) * 8;
            sh8 b0 = *(const sh8*)&Bl[cur][(r     ) * 64 + chb];
            sh8 b1 = *(const sh8*)&Bl[cur][(r + 16) * 64 + chb];
            sh8 b2v = *(const sh8*)&Bl[cur][(r + 32) * 64 + chb];
            sh8 b3 = *(const sh8*)&Bl[cur][(r + 48) * 64 + chb];
            acc0 = __builtin_amdgcn_mfma_f32_16x16x32_bf16(af.v, b0,  acc0, 0, 0, 0);
            acc1 = __builtin_amdgcn_mfma_f32_16x16x32_bf16(af.v, b1,  acc1, 0, 0, 0);
            acc2 = __builtin_amdgcn_mfma_f32_16x16x32_bf16(af.v, b2v, acc2, 0, 0, 0);
            acc3 = __builtin_amdgcn_mfma_f32_16x16x32_bf16(af.v, b3,  acc3, 0, 0, 0);
        }
        __syncthreads();   // drains vmcnt(0): next-tile stage has landed
    }
    #undef STAGE

    // write this slab's partial (C/D layout m89: col = lane&15, row = q*4+reg)
    float* tp = tpart + (size_t)blockIdx.y * N * 64;
    int growb = r0 + wave * 16 + q * 4;
    #pragma unroll
    for (int rr = 0; rr < 4; ++rr) {
        tp[(size_t)(growb + rr) * 64 + r     ] = acc0[rr];
        tp[(size_t)(growb + rr) * 64 + r + 16] = acc1[rr];
        tp[(size_t)(growb + rr) * 64 + r + 32] = acc2[rr];
        tp[(size_t)(growb + rr) * 64 + r + 48] = acc3[rr];
    }

    // --- threadfence reduction: last slab of this rowgroup does the epilogue
    __threadfence();                      // release our tpart stores (all threads)
    __syncthreads();
    if (tid == 0)
        lastf = (atomicAdd(&cnt[blockIdx.x], 1u) == KSPLIT - 1) ? 1u : 0u;
    __syncthreads();
    if (lastf == 0) return;
    __threadfence();                      // acquire other blocks' tpart stores

    float* ts = (float*)&Bl[0][0];        // 16 KB alias; Bl dead after loop
    for (int v = tid; v < 64 * 64; v += 256) {
        int rr = v >> 6, cc = v & 63;
        float sum = 0.f;
        #pragma unroll
        for (int kb = 0; kb < KSPLIT; ++kb)   // fixed order -> deterministic
            sum += tpart[(size_t)kb * N * 64 + (size_t)(r0 + rr) * 64 + cc];
        ts[v] = sum;
    }
    __syncthreads();
    int c = tid & 63, rg = tid >> 6;
    float bc = b2[c];
    for (int rr = rg * 16; rr < rg * 16 + 16; ++rr) {
        float acc = 0.f;
        #pragma unroll 8
        for (int cc = 0; cc < 64; ++cc)
            acc += ts[rr * 64 + cc] * W2[cc * 64 + c];   // ts broadcast, W2 coalesced
        float dv = deg[r0 + rr];
        float si = 1.0f / sqrtf(fmaxf(dv + 1.0f, 1.0f));
        out[(size_t)(r0 + rr) * 64 + c] = si * acc + bc;
    }
}

extern "C" void kernel_launch(void* const* d_in, const int* in_sizes, int n_in,
                              void* d_out, int out_size, void* d_ws, size_t ws_size,
                              hipStream_t stream) {
    const float* adj = (const float*)d_in[0];
    const float* W1  = (const float*)d_in[1];
    const float* b1  = (const float*)d_in[2];
    const float* W2  = (const float*)d_in[3];
    const float* b2  = (const float*)d_in[4];
    float* out = (float*)d_out;

    char* ws = (char*)d_ws;
    unsigned char*  abf = (unsigned char*)ws;                               // 64 MB
    unsigned short* gT  = (unsigned short*)(ws + (size_t)N * N);            // 1 MB
    float* tpart = (float*)(ws + (size_t)N * N + (size_t)64 * N * 2);       // 16 MB
    float* deg = tpart + (size_t)KSPLIT * N * 64;                           // 32 KB
    unsigned* cnt = (unsigned*)(deg + N);                                   // 512 B

    hipLaunchKernelGGL(k_deg_conv, dim3(N),     dim3(256), 0, stream, adj, abf, deg, cnt);
    hipLaunchKernelGGL(k_layer1,   dim3(N / 4), dim3(256), 0, stream, abf, deg, W1, b1, gT);
    hipLaunchKernelGGL(k_layer2,   dim3(N / 64, KSPLIT), dim3(256), 0, stream,
                       abf, gT, deg, W2, b2, tpart, cnt, out);
}

// Round 11
// 177.263 us; speedup vs baseline: 2.4084x; 1.4358x over previous
//
#include <hip/hip_runtime.h>
#include <stdint.h>

#define N 8192
#define KSPLIT 8               // K-slabs for k_layer2a
#define BK 64                  // K elems per LDS tile
#define KPB (N / KSPLIT)       // 1024 K per block
#define TILES (KPB / BK)       // 16 tiles per block

typedef __attribute__((ext_vector_type(8))) short sh8;
typedef __attribute__((ext_vector_type(4))) float f32x4;
typedef __attribute__((ext_vector_type(2))) float f32x2;

static __device__ __forceinline__ unsigned short f2bf(float f) {
    union { float f; unsigned u; } v; v.f = f;
    unsigned r = v.u + 0x7FFF + ((v.u >> 16) & 1);   // round-to-nearest-even
    return (unsigned short)(r >> 16);
}

static __device__ __forceinline__ float bflo(unsigned u) {
    union { unsigned u; float f; } v; v.u = u << 16;
    return v.f;
}

static __device__ __forceinline__ float bfhi(unsigned u) {
    union { unsigned u; float f; } v; v.u = u & 0xFFFF0000u;
    return v.f;
}

static __device__ __forceinline__ unsigned fbits(float f) {
    union { float f; unsigned u; } v; v.f = f;
    return v.u;
}

static __device__ __forceinline__ void glds16(const void* g, void* l) {
    __builtin_amdgcn_global_load_lds(
        (const __attribute__((address_space(1))) void*)g,
        (__attribute__((address_space(3))) void*)l, 16, 0, 0);
}

// Pass 1 (fused deg + scalars): deg[i] = row-sum of adj; fp8 e4m3 copy of
// (adj+I). deg published via device-scope atomicExch (coherent point, NO
// threadfence -- R10 lesson: per-block fences serialize L2 writebacks).
// The last block (atomic counter) computes gmax + packed yb.
__global__ __launch_bounds__(256) void k_deg_conv(const float* __restrict__ adj,
        unsigned char* __restrict__ abf, float* __restrict__ deg,
        unsigned* __restrict__ cnt, unsigned* __restrict__ yb) {
    int row = blockIdx.x;
    int t = threadIdx.x;
    int wave = t >> 6, lane = t & 63;
    const float* arow = adj + (size_t)row * N;
    unsigned* brow = (unsigned*)(abf + (size_t)row * N);
    __shared__ float red4[4];
    __shared__ unsigned lastf;
    float sum = 0.f;
    #pragma unroll
    for (int it = 0; it < N / 1024; ++it) {      // 8 iters of float4 per thread
        int j = (it * 256 + t) * 4;
        float4 v = *(const float4*)(arow + j);
        sum += v.x + v.y + v.z + v.w;
        int d = row - j;                          // diag lands here iff d in [0,4)
        float x0 = v.x + ((d == 0) ? 1.f : 0.f);
        float x1 = v.y + ((d == 1) ? 1.f : 0.f);
        float x2 = v.z + ((d == 2) ? 1.f : 0.f);
        float x3 = v.w + ((d == 3) ? 1.f : 0.f);
        unsigned p = __builtin_amdgcn_cvt_pk_fp8_f32(x0, x1, 0, false);
        p = __builtin_amdgcn_cvt_pk_fp8_f32(x2, x3, p, true);
        brow[it * 256 + t] = p;                   // 4 fp8 per u32, coalesced
    }
    #pragma unroll
    for (int m = 1; m < 64; m <<= 1) sum += __shfl_xor(sum, m);
    if (lane == 0) red4[wave] = sum;
    __syncthreads();
    if (t == 0) {
        float tot = red4[0] + red4[1] + red4[2] + red4[3];
        atomicExch(&deg[row], tot);               // publish at coherent point
        asm volatile("s_waitcnt vmcnt(0)" ::: "memory");  // exch acked first
        lastf = (atomicAdd(cnt, 1u) == (unsigned)(N - 1)) ? 1u : 0u;
    }
    __syncthreads();
    if (lastf == 0) return;

    // ---- last block only: gmax + packed y (reads deg via agent atomics,
    // which bypass any stale per-XCD L2 lines) ----
    float m = 1.0f;
    for (int it = 0; it < N / 256; ++it) {
        float d = __hip_atomic_load(&deg[it * 256 + t],
                                    __ATOMIC_RELAXED, __HIP_MEMORY_SCOPE_AGENT);
        m = fmaxf(m, d);
    }
    #pragma unroll
    for (int o = 1; o < 64; o <<= 1) m = fmaxf(m, __shfl_xor(m, o));
    if (lane == 0) red4[wave] = m;
    __syncthreads();
    float gmax = fmaxf(fmaxf(red4[0], red4[1]), fmaxf(red4[2], red4[3]));
    for (int it = 0; it < N / 256; ++it) {
        int i = it * 256 + t;
        float d = __hip_atomic_load(&deg[i],
                                    __ATOMIC_RELAXED, __HIP_MEMORY_SCOPE_AGENT);
        float si = 1.0f / sqrtf(fmaxf(d + 1.0f, 1.0f));
        unsigned lo = f2bf(si);
        unsigned hi = f2bf(si * (d / gmax));
        yb[i] = (hi << 16) | lo;                  // plain store; next-kernel edge
    }
}

// Pass 2: one wave per row. z = a_row . [y0, y1] (a fp8, y packed bf16x2);
// h1 = relu(s_i*z@W1 + b1); store gT[c][i] = bf16(s_i * h1[i][c]).
__global__ __launch_bounds__(256) void k_layer1(const unsigned char* __restrict__ abf,
        const unsigned* __restrict__ yb, const float* __restrict__ deg,
        const float* __restrict__ W1, const float* __restrict__ b1,
        unsigned short* __restrict__ gT) {
    int wave = threadIdx.x >> 6;
    int lane = threadIdx.x & 63;
    int row = blockIdx.x * 4 + wave;
    const unsigned char* arow = abf + (size_t)row * N;
    float z0 = 0.f, z1 = 0.f;
    #pragma unroll 4
    for (int it = 0; it < N / 512; ++it) {   // 16 iters, 8 elems/lane/iter
        int j = it * 512 + lane * 8;
        uint2 a8 = *(const uint2*)(arow + j);
        uint4 w0 = *(const uint4*)(yb + j);
        uint4 w1 = *(const uint4*)(yb + j + 4);
        f32x2 c01 = __builtin_amdgcn_cvt_pk_f32_fp8((int)a8.x, false);
        f32x2 c23 = __builtin_amdgcn_cvt_pk_f32_fp8((int)a8.x, true);
        f32x2 c45 = __builtin_amdgcn_cvt_pk_f32_fp8((int)a8.y, false);
        f32x2 c67 = __builtin_amdgcn_cvt_pk_f32_fp8((int)a8.y, true);
        z0 += c01.x * bflo(w0.x) + c01.y * bflo(w0.y)
            + c23.x * bflo(w0.z) + c23.y * bflo(w0.w)
            + c45.x * bflo(w1.x) + c45.y * bflo(w1.y)
            + c67.x * bflo(w1.z) + c67.y * bflo(w1.w);
        z1 += c01.x * bfhi(w0.x) + c01.y * bfhi(w0.y)
            + c23.x * bfhi(w0.z) + c23.y * bfhi(w0.w)
            + c45.x * bfhi(w1.x) + c45.y * bfhi(w1.y)
            + c67.x * bfhi(w1.z) + c67.y * bfhi(w1.w);
    }
    #pragma unroll
    for (int o = 1; o < 64; o <<= 1) {
        z0 += __shfl_xor(z0, o);
        z1 += __shfl_xor(z1, o);
    }
    float dv = deg[row];
    float si = 1.0f / sqrtf(fmaxf(dv + 1.0f, 1.0f));   // bit-identical recompute
    float h = si * (z0 * W1[lane] + z1 * W1[64 + lane]) + b1[lane];
    h = fmaxf(h, 0.f);
    gT[(size_t)lane * N + row] = f2bf(si * h);
}

// Pass 3a: partial t = A @ g over a K-slab. A fp8 in LDS (exact-converted to
// bf16 in regs via v_perm), g bf16 in LDS; bf16 MFMA 16x16x32.
__global__ __launch_bounds__(256) void k_layer2a(const unsigned char* __restrict__ abf,
        const unsigned short* __restrict__ gT, float* __restrict__ tpart) {
    __shared__ unsigned char  Al[2][64 * 64];    // 4 KB each
    __shared__ unsigned short Bl[2][64 * 64];    // 8 KB each
    int tid = threadIdx.x;
    int wave = tid >> 6, lane = tid & 63;
    int r0 = blockIdx.x * 64;
    int kbase0 = blockIdx.y * KPB;

    int r = lane & 15, q = lane >> 4;

    f32x4 acc0 = {0,0,0,0}, acc1 = {0,0,0,0}, acc2 = {0,0,0,0}, acc3 = {0,0,0,0};

    #define STAGE(buf, kbase)                                                   \
        do {                                                                    \
            {                                                                   \
                int idx = tid;                                                  \
                int srow = idx >> 2, sch = (idx & 3) ^ (srow & 3);              \
                glds16(abf + (size_t)(r0 + srow) * N + (kbase) + sch * 16,      \
                       &Al[buf][idx * 16]);                                     \
            }                                                                   \
            _Pragma("unroll")                                                   \
            for (int i = 0; i < 2; ++i) {                                       \
                int idx = i * 256 + tid;                                        \
                int srow = idx >> 3, sch = (idx & 7) ^ (srow & 7);              \
                glds16(gT + (size_t)srow * N + (kbase) + sch * 8,               \
                       &Bl[buf][idx * 8]);                                      \
            }                                                                   \
        } while (0)

    STAGE(0, kbase0);
    __syncthreads();

    for (int t = 0; t < TILES; ++t) {
        int cur = t & 1;
        if (t + 1 < TILES) STAGE(cur ^ 1, kbase0 + (t + 1) * BK);
        int arow = wave * 16 + r;
        #pragma unroll
        for (int ks = 0; ks < 2; ++ks) {            // 2 K-steps of 32 per tile
            int acho = (((ks * 2 + (q >> 1)) ^ (arow & 3)) * 16) + (q & 1) * 8;
            uint2 a8 = *(const uint2*)&Al[cur][arow * 64 + acho];
            f32x2 c01 = __builtin_amdgcn_cvt_pk_f32_fp8((int)a8.x, false);
            f32x2 c23 = __builtin_amdgcn_cvt_pk_f32_fp8((int)a8.x, true);
            f32x2 c45 = __builtin_amdgcn_cvt_pk_f32_fp8((int)a8.y, false);
            f32x2 c67 = __builtin_amdgcn_cvt_pk_f32_fp8((int)a8.y, true);
            union { unsigned u[4]; sh8 v; } af;     // fp8 ⊂ bf16: exact repack
            af.u[0] = __builtin_amdgcn_perm(fbits(c01.y), fbits(c01.x), 0x07060302);
            af.u[1] = __builtin_amdgcn_perm(fbits(c23.y), fbits(c23.x), 0x07060302);
            af.u[2] = __builtin_amdgcn_perm(fbits(c45.y), fbits(c45.x), 0x07060302);
            af.u[3] = __builtin_amdgcn_perm(fbits(c67.y), fbits(c67.x), 0x07060302);
            int chb = ((ks * 4 + q) ^ (r & 7)) * 8;
            sh8 b0 = *(const sh8*)&Bl[cur][(r     ) * 64 + chb];
            sh8 b1 = *(const sh8*)&Bl[cur][(r + 16) * 64 + chb];
            sh8 b2v = *(const sh8*)&Bl[cur][(r + 32) * 64 + chb];
            sh8 b3 = *(const sh8*)&Bl[cur][(r + 48) * 64 + chb];
            acc0 = __builtin_amdgcn_mfma_f32_16x16x32_bf16(af.v, b0,  acc0, 0, 0, 0);
            acc1 = __builtin_amdgcn_mfma_f32_16x16x32_bf16(af.v, b1,  acc1, 0, 0, 0);
            acc2 = __builtin_amdgcn_mfma_f32_16x16x32_bf16(af.v, b2v, acc2, 0, 0, 0);
            acc3 = __builtin_amdgcn_mfma_f32_16x16x32_bf16(af.v, b3,  acc3, 0, 0, 0);
        }
        __syncthreads();   // drains vmcnt(0): next-tile stage has landed
    }
    #undef STAGE

    // C/D layout (m89-verified): col = lane&15, row = (lane>>4)*4 + reg
    float* tp = tpart + (size_t)blockIdx.y * N * 64;
    int growb = r0 + wave * 16 + q * 4;
    #pragma unroll
    for (int rr = 0; rr < 4; ++rr) {
        tp[(size_t)(growb + rr) * 64 + r     ] = acc0[rr];
        tp[(size_t)(growb + rr) * 64 + r + 16] = acc1[rr];
        tp[(size_t)(growb + rr) * 64 + r + 32] = acc2[rr];
        tp[(size_t)(growb + rr) * 64 + r + 48] = acc3[rr];
    }
}

// Pass 3b: t = sum of KSPLIT partials; out = s .* (t @ W2) + b2.
__global__ __launch_bounds__(256) void k_layer2b(const float* __restrict__ tpart,
        const float* __restrict__ deg, const float* __restrict__ W2,
        const float* __restrict__ b2, float* __restrict__ out) {
    __shared__ float ts[4][64];
    int tid = threadIdx.x;
    int r0 = blockIdx.x * 4;
    int rg = tid >> 6, c = tid & 63;
    float v = 0.f;
    #pragma unroll
    for (int kb = 0; kb < KSPLIT; ++kb)
        v += tpart[(size_t)kb * N * 64 + (size_t)(r0 + rg) * 64 + c];
    ts[rg][c] = v;
    __syncthreads();
    float acc = 0.f;
    #pragma unroll 8
    for (int cc = 0; cc < 64; ++cc)
        acc += ts[rg][cc] * W2[cc * 64 + c];
    int row = r0 + rg;
    float dv = deg[row];
    float si = 1.0f / sqrtf(fmaxf(dv + 1.0f, 1.0f));
    out[(size_t)row * 64 + c] = si * acc + b2[c];
}

extern "C" void kernel_launch(void* const* d_in, const int* in_sizes, int n_in,
                              void* d_out, int out_size, void* d_ws, size_t ws_size,
                              hipStream_t stream) {
    const float* adj = (const float*)d_in[0];
    const float* W1  = (const float*)d_in[1];
    const float* b1  = (const float*)d_in[2];
    const float* W2  = (const float*)d_in[3];
    const float* b2  = (const float*)d_in[4];
    float* out = (float*)d_out;

    char* ws = (char*)d_ws;
    unsigned char*  abf = (unsigned char*)ws;                               // 64 MB
    unsigned short* gT  = (unsigned short*)(ws + (size_t)N * N);            // 1 MB
    float* tpart = (float*)(ws + (size_t)N * N + (size_t)64 * N * 2);       // 16 MB
    float* deg = tpart + (size_t)KSPLIT * N * 64;                           // 32 KB
    unsigned* cnt = (unsigned*)(deg + N);
    unsigned* yb  = (unsigned*)((char*)cnt + 64);                           // 32 KB

    hipMemsetAsync(cnt, 0, sizeof(unsigned), stream);   // poison-proof counter
    hipLaunchKernelGGL(k_deg_conv, dim3(N),     dim3(256), 0, stream,
                       adj, abf, deg, cnt, yb);
    hipLaunchKernelGGL(k_layer1,   dim3(N / 4), dim3(256), 0, stream,
                       abf, yb, deg, W1, b1, gT);
    hipLaunchKernelGGL(k_layer2a,  dim3(N / 64, KSPLIT), dim3(256), 0, stream,
                       abf, gT, tpart);
    hipLaunchKernelGGL(k_layer2b,  dim3(N / 4), dim3(256), 0, stream,
                       tpart, deg, W2, b2, out);
}

// Round 12
// 163.465 us; speedup vs baseline: 2.6117x; 1.0844x over previous
//
#include <hip/hip_runtime.h>
#include <stdint.h>

#define N 8192
#define KSPLIT 8               // K-slabs for k_layer2a
#define BK 64                  // K elems per LDS tile
#define KPB (N / KSPLIT)       // 1024 K per block
#define TILES (KPB / BK)       // 16 tiles per block

typedef __attribute__((ext_vector_type(8))) short sh8;
typedef __attribute__((ext_vector_type(4))) float f32x4;
typedef __attribute__((ext_vector_type(2))) float f32x2;

static __device__ __forceinline__ unsigned short f2bf(float f) {
    union { float f; unsigned u; } v; v.f = f;
    unsigned r = v.u + 0x7FFF + ((v.u >> 16) & 1);   // round-to-nearest-even
    return (unsigned short)(r >> 16);
}

static __device__ __forceinline__ float bflo(unsigned u) {
    union { unsigned u; float f; } v; v.u = u << 16;
    return v.f;
}

static __device__ __forceinline__ float bfhi(unsigned u) {
    union { unsigned u; float f; } v; v.u = u & 0xFFFF0000u;
    return v.f;
}

static __device__ __forceinline__ unsigned fbits(float f) {
    union { float f; unsigned u; } v; v.f = f;
    return v.u;
}

static __device__ __forceinline__ void glds16(const void* g, void* l) {
    __builtin_amdgcn_global_load_lds(
        (const __attribute__((address_space(1))) void*)g,
        (__attribute__((address_space(3))) void*)l, 16, 0, 0);
}

// Pass 1: deg[i] = row-sum of adj (f32); fp8 e4m3 copy of (adj + I).
// Tail (thread 0): yb[row] = pack(bf16(s*deg), bf16(s)) -- depends only on
// this row's deg -- and atomicMax of float-bits(max(deg,1)) into gmaxi.
// Positive floats order as signed ints; 0xAA..A poison is negative -> safe
// first-launch init; same value every replay -> idempotent/deterministic.
// NO memset, NO fence (R10/R11 lessons: both serialize L2 writebacks).
__global__ __launch_bounds__(256) void k_deg_conv(const float* __restrict__ adj,
        unsigned char* __restrict__ abf, float* __restrict__ deg,
        unsigned* __restrict__ yb, int* __restrict__ gmaxi) {
    int row = blockIdx.x;
    int t = threadIdx.x;
    int wave = t >> 6, lane = t & 63;
    const float* arow = adj + (size_t)row * N;
    unsigned* brow = (unsigned*)(abf + (size_t)row * N);
    __shared__ float red4[4];
    float sum = 0.f;
    #pragma unroll
    for (int it = 0; it < N / 1024; ++it) {      // 8 iters of float4 per thread
        int j = (it * 256 + t) * 4;
        float4 v = *(const float4*)(arow + j);
        sum += v.x + v.y + v.z + v.w;
        int d = row - j;                          // diag lands here iff d in [0,4)
        float x0 = v.x + ((d == 0) ? 1.f : 0.f);
        float x1 = v.y + ((d == 1) ? 1.f : 0.f);
        float x2 = v.z + ((d == 2) ? 1.f : 0.f);
        float x3 = v.w + ((d == 3) ? 1.f : 0.f);
        unsigned p = __builtin_amdgcn_cvt_pk_fp8_f32(x0, x1, 0, false);
        p = __builtin_amdgcn_cvt_pk_fp8_f32(x2, x3, p, true);
        brow[it * 256 + t] = p;                   // 4 fp8 per u32, coalesced
    }
    #pragma unroll
    for (int m = 1; m < 64; m <<= 1) sum += __shfl_xor(sum, m);
    if (lane == 0) red4[wave] = sum;
    __syncthreads();
    if (t == 0) {
        float tot = red4[0] + red4[1] + red4[2] + red4[3];
        deg[row] = tot;
        float si = 1.0f / sqrtf(fmaxf(tot + 1.0f, 1.0f));
        yb[row] = ((unsigned)f2bf(si * tot) << 16) | f2bf(si);
        atomicMax(gmaxi, (int)fbits(fmaxf(tot, 1.0f)));   // no return use
    }
}

// Pass 2: one wave per row. z0 = a.s, z1 = (a.(s*deg))/gmax (a fp8, y bf16x2);
// h1 = relu(s_i*(z0*W1[0,c]+z1*W1[1,c]) + b1); gT[c][i] = bf16(s_i * h1).
__global__ __launch_bounds__(256) void k_layer1(const unsigned char* __restrict__ abf,
        const unsigned* __restrict__ yb, const float* __restrict__ deg,
        const int* __restrict__ gmaxi, const float* __restrict__ W1,
        const float* __restrict__ b1, unsigned short* __restrict__ gT) {
    int wave = threadIdx.x >> 6;
    int lane = threadIdx.x & 63;
    int row = blockIdx.x * 4 + wave;
    const unsigned char* arow = abf + (size_t)row * N;
    float z0 = 0.f, z1 = 0.f;
    #pragma unroll 4
    for (int it = 0; it < N / 512; ++it) {   // 16 iters, 8 elems/lane/iter
        int j = it * 512 + lane * 8;
        uint2 a8 = *(const uint2*)(arow + j);
        uint4 w0 = *(const uint4*)(yb + j);
        uint4 w1 = *(const uint4*)(yb + j + 4);
        f32x2 c01 = __builtin_amdgcn_cvt_pk_f32_fp8((int)a8.x, false);
        f32x2 c23 = __builtin_amdgcn_cvt_pk_f32_fp8((int)a8.x, true);
        f32x2 c45 = __builtin_amdgcn_cvt_pk_f32_fp8((int)a8.y, false);
        f32x2 c67 = __builtin_amdgcn_cvt_pk_f32_fp8((int)a8.y, true);
        z0 += c01.x * bflo(w0.x) + c01.y * bflo(w0.y)
            + c23.x * bflo(w0.z) + c23.y * bflo(w0.w)
            + c45.x * bflo(w1.x) + c45.y * bflo(w1.y)
            + c67.x * bflo(w1.z) + c67.y * bflo(w1.w);
        z1 += c01.x * bfhi(w0.x) + c01.y * bfhi(w0.y)
            + c23.x * bfhi(w0.z) + c23.y * bfhi(w0.w)
            + c45.x * bfhi(w1.x) + c45.y * bfhi(w1.y)
            + c67.x * bfhi(w1.z) + c67.y * bfhi(w1.w);
    }
    #pragma unroll
    for (int o = 1; o < 64; o <<= 1) {
        z0 += __shfl_xor(z0, o);
        z1 += __shfl_xor(z1, o);
    }
    union { int i; float f; } gm; gm.i = *gmaxi;       // final after k1 boundary
    z1 = z1 / gm.f;                                    // = a.(s*deg/gmax)
    float dv = deg[row];
    float si = 1.0f / sqrtf(fmaxf(dv + 1.0f, 1.0f));
    float h = si * (z0 * W1[lane] + z1 * W1[64 + lane]) + b1[lane];
    h = fmaxf(h, 0.f);
    gT[(size_t)lane * N + row] = f2bf(si * h);
}

// Pass 3a: partial t = A @ g over a K-slab. A fp8 in LDS (exact-converted to
// bf16 in regs via v_perm), g bf16 in LDS; bf16 MFMA 16x16x32.
__global__ __launch_bounds__(256) void k_layer2a(const unsigned char* __restrict__ abf,
        const unsigned short* __restrict__ gT, float* __restrict__ tpart) {
    __shared__ unsigned char  Al[2][64 * 64];    // 4 KB each
    __shared__ unsigned short Bl[2][64 * 64];    // 8 KB each
    int tid = threadIdx.x;
    int wave = tid >> 6, lane = tid & 63;
    int r0 = blockIdx.x * 64;
    int kbase0 = blockIdx.y * KPB;

    int r = lane & 15, q = lane >> 4;

    f32x4 acc0 = {0,0,0,0}, acc1 = {0,0,0,0}, acc2 = {0,0,0,0}, acc3 = {0,0,0,0};

    #define STAGE(buf, kbase)                                                   \
        do {                                                                    \
            {                                                                   \
                int idx = tid;                                                  \
                int srow = idx >> 2, sch = (idx & 3) ^ (srow & 3);              \
                glds16(abf + (size_t)(r0 + srow) * N + (kbase) + sch * 16,      \
                       &Al[buf][idx * 16]);                                     \
            }                                                                   \
            _Pragma("unroll")                                                   \
            for (int i = 0; i < 2; ++i) {                                       \
                int idx = i * 256 + tid;                                        \
                int srow = idx >> 3, sch = (idx & 7) ^ (srow & 7);              \
                glds16(gT + (size_t)srow * N + (kbase) + sch * 8,               \
                       &Bl[buf][idx * 8]);                                      \
            }                                                                   \
        } while (0)

    STAGE(0, kbase0);
    __syncthreads();

    for (int t = 0; t < TILES; ++t) {
        int cur = t & 1;
        if (t + 1 < TILES) STAGE(cur ^ 1, kbase0 + (t + 1) * BK);
        int arow = wave * 16 + r;
        #pragma unroll
        for (int ks = 0; ks < 2; ++ks) {            // 2 K-steps of 32 per tile
            int acho = (((ks * 2 + (q >> 1)) ^ (arow & 3)) * 16) + (q & 1) * 8;
            uint2 a8 = *(const uint2*)&Al[cur][arow * 64 + acho];
            f32x2 c01 = __builtin_amdgcn_cvt_pk_f32_fp8((int)a8.x, false);
            f32x2 c23 = __builtin_amdgcn_cvt_pk_f32_fp8((int)a8.x, true);
            f32x2 c45 = __builtin_amdgcn_cvt_pk_f32_fp8((int)a8.y, false);
            f32x2 c67 = __builtin_amdgcn_cvt_pk_f32_fp8((int)a8.y, true);
            union { unsigned u[4]; sh8 v; } af;     // fp8 ⊂ bf16: exact repack
            af.u[0] = __builtin_amdgcn_perm(fbits(c01.y), fbits(c01.x), 0x07060302);
            af.u[1] = __builtin_amdgcn_perm(fbits(c23.y), fbits(c23.x), 0x07060302);
            af.u[2] = __builtin_amdgcn_perm(fbits(c45.y), fbits(c45.x), 0x07060302);
            af.u[3] = __builtin_amdgcn_perm(fbits(c67.y), fbits(c67.x), 0x07060302);
            int chb = ((ks * 4 + q) ^ (r & 7)) * 8;
            sh8 b0 = *(const sh8*)&Bl[cur][(r     ) * 64 + chb];
            sh8 b1 = *(const sh8*)&Bl[cur][(r + 16) * 64 + chb];
            sh8 b2v = *(const sh8*)&Bl[cur][(r + 32) * 64 + chb];
            sh8 b3 = *(const sh8*)&Bl[cur][(r + 48) * 64 + chb];
            acc0 = __builtin_amdgcn_mfma_f32_16x16x32_bf16(af.v, b0,  acc0, 0, 0, 0);
            acc1 = __builtin_amdgcn_mfma_f32_16x16x32_bf16(af.v, b1,  acc1, 0, 0, 0);
            acc2 = __builtin_amdgcn_mfma_f32_16x16x32_bf16(af.v, b2v, acc2, 0, 0, 0);
            acc3 = __builtin_amdgcn_mfma_f32_16x16x32_bf16(af.v, b3,  acc3, 0, 0, 0);
        }
        __syncthreads();   // drains vmcnt(0): next-tile stage has landed
    }
    #undef STAGE

    // C/D layout (m89-verified): col = lane&15, row = (lane>>4)*4 + reg
    float* tp = tpart + (size_t)blockIdx.y * N * 64;
    int growb = r0 + wave * 16 + q * 4;
    #pragma unroll
    for (int rr = 0; rr < 4; ++rr) {
        tp[(size_t)(growb + rr) * 64 + r     ] = acc0[rr];
        tp[(size_t)(growb + rr) * 64 + r + 16] = acc1[rr];
        tp[(size_t)(growb + rr) * 64 + r + 32] = acc2[rr];
        tp[(size_t)(growb + rr) * 64 + r + 48] = acc3[rr];
    }
}

// Pass 3b: t = sum of KSPLIT partials; out = s .* (t @ W2) + b2.
__global__ __launch_bounds__(256) void k_layer2b(const float* __restrict__ tpart,
        const float* __restrict__ deg, const float* __restrict__ W2,
        const float* __restrict__ b2, float* __restrict__ out) {
    __shared__ float ts[4][64];
    int tid = threadIdx.x;
    int r0 = blockIdx.x * 4;
    int rg = tid >> 6, c = tid & 63;
    float v = 0.f;
    #pragma unroll
    for (int kb = 0; kb < KSPLIT; ++kb)
        v += tpart[(size_t)kb * N * 64 + (size_t)(r0 + rg) * 64 + c];
    ts[rg][c] = v;
    __syncthreads();
    float acc = 0.f;
    #pragma unroll 8
    for (int cc = 0; cc < 64; ++cc)
        acc += ts[rg][cc] * W2[cc * 64 + c];
    int row = r0 + rg;
    float dv = deg[row];
    float si = 1.0f / sqrtf(fmaxf(dv + 1.0f, 1.0f));
    out[(size_t)row * 64 + c] = si * acc + b2[c];
}

extern "C" void kernel_launch(void* const* d_in, const int* in_sizes, int n_in,
                              void* d_out, int out_size, void* d_ws, size_t ws_size,
                              hipStream_t stream) {
    const float* adj = (const float*)d_in[0];
    const float* W1  = (const float*)d_in[1];
    const float* b1  = (const float*)d_in[2];
    const float* W2  = (const float*)d_in[3];
    const float* b2  = (const float*)d_in[4];
    float* out = (float*)d_out;

    char* ws = (char*)d_ws;
    unsigned char*  abf = (unsigned char*)ws;                               // 64 MB
    unsigned short* gT  = (unsigned short*)(ws + (size_t)N * N);            // 1 MB
    float* tpart = (float*)(ws + (size_t)N * N + (size_t)64 * N * 2);       // 16 MB
    float* deg = tpart + (size_t)KSPLIT * N * 64;                           // 32 KB
    unsigned* yb = (unsigned*)(deg + N);                                    // 32 KB
    int* gmaxi = (int*)(yb + N);                                            // 4 B

    hipLaunchKernelGGL(k_deg_conv, dim3(N),     dim3(256), 0, stream,
                       adj, abf, deg, yb, gmaxi);
    hipLaunchKernelGGL(k_layer1,   dim3(N / 4), dim3(256), 0, stream,
                       abf, yb, deg, gmaxi, W1, b1, gT);
    hipLaunchKernelGGL(k_layer2a,  dim3(N / 64, KSPLIT), dim3(256), 0, stream,
                       abf, gT, tpart);
    hipLaunchKernelGGL(k_layer2b,  dim3(N / 4), dim3(256), 0, stream,
                       tpart, deg, W2, b2, out);
}

// Round 13
// 120.648 us; speedup vs baseline: 3.5386x; 1.3549x over previous
//
#include <hip/hip_runtime.h>
#include <stdint.h>

#define N 8192
#define KSPLIT 8               // K-slabs for k_layer2a
#define BK 64                  // K elems per LDS tile
#define KPB (N / KSPLIT)       // 1024 K per block
#define TILES (KPB / BK)       // 16 tiles per block

typedef __attribute__((ext_vector_type(8))) short sh8;
typedef __attribute__((ext_vector_type(4))) float f32x4;
typedef __attribute__((ext_vector_type(2))) float f32x2;

static __device__ __forceinline__ unsigned short f2bf(float f) {
    union { float f; unsigned u; } v; v.f = f;
    unsigned r = v.u + 0x7FFF + ((v.u >> 16) & 1);   // round-to-nearest-even
    return (unsigned short)(r >> 16);
}

static __device__ __forceinline__ float bflo(unsigned u) {
    union { unsigned u; float f; } v; v.u = u << 16;
    return v.f;
}

static __device__ __forceinline__ float bfhi(unsigned u) {
    union { unsigned u; float f; } v; v.u = u & 0xFFFF0000u;
    return v.f;
}

static __device__ __forceinline__ unsigned fbits(float f) {
    union { float f; unsigned u; } v; v.f = f;
    return v.u;
}

static __device__ __forceinline__ void glds16(const void* g, void* l) {
    __builtin_amdgcn_global_load_lds(
        (const __attribute__((address_space(1))) void*)g,
        (__attribute__((address_space(3))) void*)l, 16, 0, 0);
}

// Pass 1: deg[i] = row-sum of adj (exact f32); write fp8 e4m3 copy of (adj + I).
// R8-proven form: block-per-row, LDS-tree reduce, NO atomics/fences (R10-R12
// lessons: all global-sync shortcuts on MI355X cost 15-60x their nominal work).
__global__ __launch_bounds__(256) void k_deg_conv(const float* __restrict__ adj,
        unsigned char* __restrict__ abf, float* __restrict__ deg) {
    int row = blockIdx.x;
    const float* arow = adj + (size_t)row * N;
    unsigned* brow = (unsigned*)(abf + (size_t)row * N);
    int t = threadIdx.x;
    float sum = 0.f;
    #pragma unroll
    for (int it = 0; it < N / 1024; ++it) {      // 8 iters of float4 per thread
        int j = (it * 256 + t) * 4;
        float4 v = *(const float4*)(arow + j);
        sum += v.x + v.y + v.z + v.w;
        int d = row - j;                          // diag lands here iff d in [0,4)
        float x0 = v.x + ((d == 0) ? 1.f : 0.f);
        float x1 = v.y + ((d == 1) ? 1.f : 0.f);
        float x2 = v.z + ((d == 2) ? 1.f : 0.f);
        float x3 = v.w + ((d == 3) ? 1.f : 0.f);
        unsigned p = __builtin_amdgcn_cvt_pk_fp8_f32(x0, x1, 0, false);
        p = __builtin_amdgcn_cvt_pk_fp8_f32(x2, x3, p, true);
        brow[it * 256 + t] = p;                   // 4 fp8 per u32, coalesced
    }
    __shared__ float red[256];
    red[t] = sum; __syncthreads();
    for (int sz = 128; sz > 0; sz >>= 1) {
        if (t < sz) red[t] += red[t + sz];
        __syncthreads();
    }
    if (t == 0) deg[row] = red[0];
}

// Pass 2 (single block): gmax; s (f32); yb[j] = pack(bf16(y1), bf16(y0)).
__global__ __launch_bounds__(1024) void k_scalars(const float* __restrict__ deg,
        float* __restrict__ s, unsigned* __restrict__ yb) {
    __shared__ float red[1024];
    int t = threadIdx.x;
    float m = 1.0f;
    for (int i = t; i < N; i += 1024) m = fmaxf(m, deg[i]);
    red[t] = m; __syncthreads();
    for (int sz = 512; sz > 0; sz >>= 1) {
        if (t < sz) red[t] = fmaxf(red[t], red[t + sz]);
        __syncthreads();
    }
    float gmax = red[0];
    for (int i = t; i < N; i += 1024) {
        float d = deg[i];
        float si = 1.0f / sqrtf(fmaxf(d + 1.0f, 1.0f));
        s[i] = si;
        unsigned lo = f2bf(si);
        unsigned hi = f2bf(si * (d / gmax));
        yb[i] = (hi << 16) | lo;
    }
}

// Pass 3: one wave per row. z = a_row . [y0, y1] (a fp8, y packed bf16x2);
// h1 = relu(s_i*z@W1 + b1); store gT[c][i] = bf16(s_i * h1[i][c]).
__global__ __launch_bounds__(256) void k_layer1(const unsigned char* __restrict__ abf,
        const unsigned* __restrict__ yb, const float* __restrict__ s,
        const float* __restrict__ W1, const float* __restrict__ b1,
        unsigned short* __restrict__ gT) {
    int wave = threadIdx.x >> 6;
    int lane = threadIdx.x & 63;
    int row = blockIdx.x * 4 + wave;
    const unsigned char* arow = abf + (size_t)row * N;
    float z0 = 0.f, z1 = 0.f;
    #pragma unroll 4
    for (int it = 0; it < N / 512; ++it) {   // 16 iters, 8 elems/lane/iter
        int j = it * 512 + lane * 8;
        uint2 a8 = *(const uint2*)(arow + j);
        uint4 w0 = *(const uint4*)(yb + j);
        uint4 w1 = *(const uint4*)(yb + j + 4);
        f32x2 c01 = __builtin_amdgcn_cvt_pk_f32_fp8((int)a8.x, false);
        f32x2 c23 = __builtin_amdgcn_cvt_pk_f32_fp8((int)a8.x, true);
        f32x2 c45 = __builtin_amdgcn_cvt_pk_f32_fp8((int)a8.y, false);
        f32x2 c67 = __builtin_amdgcn_cvt_pk_f32_fp8((int)a8.y, true);
        z0 += c01.x * bflo(w0.x) + c01.y * bflo(w0.y)
            + c23.x * bflo(w0.z) + c23.y * bflo(w0.w)
            + c45.x * bflo(w1.x) + c45.y * bflo(w1.y)
            + c67.x * bflo(w1.z) + c67.y * bflo(w1.w);
        z1 += c01.x * bfhi(w0.x) + c01.y * bfhi(w0.y)
            + c23.x * bfhi(w0.z) + c23.y * bfhi(w0.w)
            + c45.x * bfhi(w1.x) + c45.y * bfhi(w1.y)
            + c67.x * bfhi(w1.z) + c67.y * bfhi(w1.w);
    }
    #pragma unroll
    for (int o = 1; o < 64; o <<= 1) {
        z0 += __shfl_xor(z0, o);
        z1 += __shfl_xor(z1, o);
    }
    float si = s[row];
    float h = si * (z0 * W1[lane] + z1 * W1[64 + lane]) + b1[lane];
    h = fmaxf(h, 0.f);
    gT[(size_t)lane * N + row] = f2bf(si * h);
}

// Pass 4a: partial t = A @ g over a K-slab. A fp8 in LDS (exact-converted to
// bf16 in regs via v_perm -- fp8 values are exact in bf16), g bf16 in LDS;
// bf16 MFMA 16x16x32. Grid (N/64, KSPLIT); 4 waves; 24 KB LDS double-buffered.
__global__ __launch_bounds__(256) void k_layer2a(const unsigned char* __restrict__ abf,
        const unsigned short* __restrict__ gT, float* __restrict__ tpart) {
    __shared__ unsigned char  Al[2][64 * 64];    // 4 KB each
    __shared__ unsigned short Bl[2][64 * 64];    // 8 KB each
    int tid = threadIdx.x;
    int wave = tid >> 6, lane = tid & 63;
    int r0 = blockIdx.x * 64;
    int kbase0 = blockIdx.y * KPB;

    int r = lane & 15, q = lane >> 4;

    f32x4 acc0 = {0,0,0,0}, acc1 = {0,0,0,0}, acc2 = {0,0,0,0}, acc3 = {0,0,0,0};

    #define STAGE(buf, kbase)                                                   \
        do {                                                                    \
            {                                                                   \
                int idx = tid;                                                  \
                int srow = idx >> 2, sch = (idx & 3) ^ (srow & 3);              \
                glds16(abf + (size_t)(r0 + srow) * N + (kbase) + sch * 16,      \
                       &Al[buf][idx * 16]);                                     \
            }                                                                   \
            _Pragma("unroll")                                                   \
            for (int i = 0; i < 2; ++i) {                                       \
                int idx = i * 256 + tid;                                        \
                int srow = idx >> 3, sch = (idx & 7) ^ (srow & 7);              \
                glds16(gT + (size_t)srow * N + (kbase) + sch * 8,               \
                       &Bl[buf][idx * 8]);                                      \
            }                                                                   \
        } while (0)

    STAGE(0, kbase0);
    __syncthreads();

    for (int t = 0; t < TILES; ++t) {
        int cur = t & 1;
        if (t + 1 < TILES) STAGE(cur ^ 1, kbase0 + (t + 1) * BK);
        int arow = wave * 16 + r;
        #pragma unroll
        for (int ks = 0; ks < 2; ++ks) {            // 2 K-steps of 32 per tile
            int acho = (((ks * 2 + (q >> 1)) ^ (arow & 3)) * 16) + (q & 1) * 8;
            uint2 a8 = *(const uint2*)&Al[cur][arow * 64 + acho];
            f32x2 c01 = __builtin_amdgcn_cvt_pk_f32_fp8((int)a8.x, false);
            f32x2 c23 = __builtin_amdgcn_cvt_pk_f32_fp8((int)a8.x, true);
            f32x2 c45 = __builtin_amdgcn_cvt_pk_f32_fp8((int)a8.y, false);
            f32x2 c67 = __builtin_amdgcn_cvt_pk_f32_fp8((int)a8.y, true);
            union { unsigned u[4]; sh8 v; } af;     // fp8 ⊂ bf16: exact repack
            af.u[0] = __builtin_amdgcn_perm(fbits(c01.y), fbits(c01.x), 0x07060302);
            af.u[1] = __builtin_amdgcn_perm(fbits(c23.y), fbits(c23.x), 0x07060302);
            af.u[2] = __builtin_amdgcn_perm(fbits(c45.y), fbits(c45.x), 0x07060302);
            af.u[3] = __builtin_amdgcn_perm(fbits(c67.y), fbits(c67.x), 0x07060302);
            int chb = ((ks * 4 + q) ^ (r & 7)) * 8;
            sh8 b0 = *(const sh8*)&Bl[cur][(r     ) * 64 + chb];
            sh8 b1 = *(const sh8*)&Bl[cur][(r + 16) * 64 + chb];
            sh8 b2v = *(const sh8*)&Bl[cur][(r + 32) * 64 + chb];
            sh8 b3 = *(const sh8*)&Bl[cur][(r + 48) * 64 + chb];
            acc0 = __builtin_amdgcn_mfma_f32_16x16x32_bf16(af.v, b0,  acc0, 0, 0, 0);
            acc1 = __builtin_amdgcn_mfma_f32_16x16x32_bf16(af.v, b1,  acc1, 0, 0, 0);
            acc2 = __builtin_amdgcn_mfma_f32_16x16x32_bf16(af.v, b2v, acc2, 0, 0, 0);
            acc3 = __builtin_amdgcn_mfma_f32_16x16x32_bf16(af.v, b3,  acc3, 0, 0, 0);
        }
        __syncthreads();   // drains vmcnt(0): next-tile stage has landed
    }
    #undef STAGE

    // C/D layout (m89-verified): col = lane&15, row = (lane>>4)*4 + reg
    float* tp = tpart + (size_t)blockIdx.y * N * 64;
    int growb = r0 + wave * 16 + q * 4;
    #pragma unroll
    for (int rr = 0; rr < 4; ++rr) {
        tp[(size_t)(growb + rr) * 64 + r     ] = acc0[rr];
        tp[(size_t)(growb + rr) * 64 + r + 16] = acc1[rr];
        tp[(size_t)(growb + rr) * 64 + r + 32] = acc2[rr];
        tp[(size_t)(growb + rr) * 64 + r + 48] = acc3[rr];
    }
}

// Pass 4b: t = sum of KSPLIT partials; out = s .* (t @ W2) + b2.
__global__ __launch_bounds__(256) void k_layer2b(const float* __restrict__ tpart,
        const float* __restrict__ s, const float* __restrict__ W2,
        const float* __restrict__ b2, float* __restrict__ out) {
    __shared__ float ts[4][64];
    int tid = threadIdx.x;
    int r0 = blockIdx.x * 4;
    int rg = tid >> 6, c = tid & 63;
    float v = 0.f;
    #pragma unroll
    for (int kb = 0; kb < KSPLIT; ++kb)
        v += tpart[(size_t)kb * N * 64 + (size_t)(r0 + rg) * 64 + c];
    ts[rg][c] = v;
    __syncthreads();
    float acc = 0.f;
    #pragma unroll 8
    for (int cc = 0; cc < 64; ++cc)
        acc += ts[rg][cc] * W2[cc * 64 + c];
    int row = r0 + rg;
    out[(size_t)row * 64 + c] = s[row] * acc + b2[c];
}

extern "C" void kernel_launch(void* const* d_in, const int* in_sizes, int n_in,
                              void* d_out, int out_size, void* d_ws, size_t ws_size,
                              hipStream_t stream) {
    const float* adj = (const float*)d_in[0];
    const float* W1  = (const float*)d_in[1];
    const float* b1  = (const float*)d_in[2];
    const float* W2  = (const float*)d_in[3];
    const float* b2  = (const float*)d_in[4];
    float* out = (float*)d_out;

    char* ws = (char*)d_ws;
    unsigned char*  abf = (unsigned char*)ws;                               // 64 MB
    unsigned short* gT  = (unsigned short*)(ws + (size_t)N * N);            // 1 MB
    float* tpart = (float*)(ws + (size_t)N * N + (size_t)64 * N * 2);       // 16 MB
    float* deg = tpart + (size_t)KSPLIT * N * 64;                           // 32 KB
    float* s   = deg + N;
    unsigned* yb = (unsigned*)(s + N);

    hipLaunchKernelGGL(k_deg_conv, dim3(N),      dim3(256),  0, stream, adj, abf, deg);
    hipLaunchKernelGGL(k_scalars,  dim3(1),      dim3(1024), 0, stream, deg, s, yb);
    hipLaunchKernelGGL(k_layer1,   dim3(N / 4),  dim3(256),  0, stream, abf, yb, s, W1, b1, gT);
    hipLaunchKernelGGL(k_layer2a,  dim3(N / 64, KSPLIT), dim3(256), 0, stream, abf, gT, tpart);
    hipLaunchKernelGGL(k_layer2b,  dim3(N / 4),  dim3(256),  0, stream, tpart, s, W2, b2, out);
}

// Round 15
// 114.212 us; speedup vs baseline: 3.7380x; 1.0564x over previous
//
#include <hip/hip_runtime.h>
#include <stdint.h>

#define N 8192
#define KSPLIT 8               // K-slabs for k_layer2a
#define BK 64                  // K elems per LDS tile
#define KPB (N / KSPLIT)       // 1024 K per block
#define TILES (KPB / BK)       // 16 tiles per block

typedef __attribute__((ext_vector_type(8))) short sh8;
typedef __attribute__((ext_vector_type(4))) float f32x4;
typedef __attribute__((ext_vector_type(2))) float f32x2;

static __device__ __forceinline__ unsigned short f2bf(float f) {
    union { float f; unsigned u; } v; v.f = f;
    unsigned r = v.u + 0x7FFF + ((v.u >> 16) & 1);   // round-to-nearest-even
    return (unsigned short)(r >> 16);
}

static __device__ __forceinline__ float bflo(unsigned u) {
    union { unsigned u; float f; } v; v.u = u << 16;
    return v.f;
}

static __device__ __forceinline__ float bfhi(unsigned u) {
    union { unsigned u; float f; } v; v.u = u & 0xFFFF0000u;
    return v.f;
}

static __device__ __forceinline__ unsigned fbits(float f) {
    union { float f; unsigned u; } v; v.f = f;
    return v.u;
}

static __device__ __forceinline__ void glds16(const void* g, void* l) {
    __builtin_amdgcn_global_load_lds(
        (const __attribute__((address_space(1))) void*)g,
        (__attribute__((address_space(3))) void*)l, 16, 0, 0);
}

// Pass 1: deg[i] = row-sum of adj (exact f32); fp8 e4m3 copy of (adj + I);
// tail writes yb[row] = pack(bf16(s*deg), bf16(s)) (per-row data, no sync --
// the R12 numeric path, validated absmax-identical; the atomicMax is gone).
// adj is streamed with NON-TEMPORAL loads (native ext_vector f32x4 -- the HIP
// float4 class is rejected by the builtin) so the freshly written abf (64 MB)
// survives in the 256 MB L3 for k_layer1/k_layer2a.
__global__ __launch_bounds__(256) void k_deg_conv(const float* __restrict__ adj,
        unsigned char* __restrict__ abf, float* __restrict__ deg,
        unsigned* __restrict__ yb) {
    int row = blockIdx.x;
    const float* arow = adj + (size_t)row * N;
    unsigned* brow = (unsigned*)(abf + (size_t)row * N);
    int t = threadIdx.x;
    float sum = 0.f;
    #pragma unroll
    for (int it = 0; it < N / 1024; ++it) {      // 8 iters of f32x4 per thread
        int j = (it * 256 + t) * 4;
        f32x4 v = __builtin_nontemporal_load((const f32x4*)(arow + j));
        sum += v.x + v.y + v.z + v.w;
        int d = row - j;                          // diag lands here iff d in [0,4)
        float x0 = v.x + ((d == 0) ? 1.f : 0.f);
        float x1 = v.y + ((d == 1) ? 1.f : 0.f);
        float x2 = v.z + ((d == 2) ? 1.f : 0.f);
        float x3 = v.w + ((d == 3) ? 1.f : 0.f);
        unsigned p = __builtin_amdgcn_cvt_pk_fp8_f32(x0, x1, 0, false);
        p = __builtin_amdgcn_cvt_pk_fp8_f32(x2, x3, p, true);
        brow[it * 256 + t] = p;                   // 4 fp8 per u32, coalesced
    }
    __shared__ float red[256];
    red[t] = sum; __syncthreads();
    for (int sz = 128; sz > 0; sz >>= 1) {
        if (t < sz) red[t] += red[t + sz];
        __syncthreads();
    }
    if (t == 0) {
        float tot = red[0];
        deg[row] = tot;
        float si = 1.0f / sqrtf(fmaxf(tot + 1.0f, 1.0f));
        yb[row] = ((unsigned)f2bf(si * tot) << 16) | f2bf(si);
    }
}

// Pass 2 (single block): gmax = max(max(deg_i,1)) only -- the pack loop moved
// into k1's tail; k3 applies the /gmax algebraically (R12-validated numerics).
__global__ __launch_bounds__(1024) void k_gmax(const float* __restrict__ deg,
        float* __restrict__ gmax) {
    __shared__ float red[1024];
    int t = threadIdx.x;
    float m = 1.0f;
    for (int i = t; i < N; i += 1024) m = fmaxf(m, deg[i]);
    red[t] = m; __syncthreads();
    for (int sz = 512; sz > 0; sz >>= 1) {
        if (t < sz) red[t] = fmaxf(red[t], red[t + sz]);
        __syncthreads();
    }
    if (t == 0) gmax[0] = red[0];
}

// Pass 3: one wave per row. z0 = a.s, z1 = a.(s*deg); then z1 /= gmax;
// h1 = relu(s_i*(z0*W1[0,c]+z1*W1[1,c]) + b1); gT[c][i] = bf16(s_i * h1).
__global__ __launch_bounds__(256) void k_layer1(const unsigned char* __restrict__ abf,
        const unsigned* __restrict__ yb, const float* __restrict__ deg,
        const float* __restrict__ gmax, const float* __restrict__ W1,
        const float* __restrict__ b1, unsigned short* __restrict__ gT) {
    int wave = threadIdx.x >> 6;
    int lane = threadIdx.x & 63;
    int row = blockIdx.x * 4 + wave;
    const unsigned char* arow = abf + (size_t)row * N;
    float z0 = 0.f, z1 = 0.f;
    #pragma unroll 4
    for (int it = 0; it < N / 512; ++it) {   // 16 iters, 8 elems/lane/iter
        int j = it * 512 + lane * 8;
        uint2 a8 = *(const uint2*)(arow + j);
        uint4 w0 = *(const uint4*)(yb + j);
        uint4 w1 = *(const uint4*)(yb + j + 4);
        f32x2 c01 = __builtin_amdgcn_cvt_pk_f32_fp8((int)a8.x, false);
        f32x2 c23 = __builtin_amdgcn_cvt_pk_f32_fp8((int)a8.x, true);
        f32x2 c45 = __builtin_amdgcn_cvt_pk_f32_fp8((int)a8.y, false);
        f32x2 c67 = __builtin_amdgcn_cvt_pk_f32_fp8((int)a8.y, true);
        z0 += c01.x * bflo(w0.x) + c01.y * bflo(w0.y)
            + c23.x * bflo(w0.z) + c23.y * bflo(w0.w)
            + c45.x * bflo(w1.x) + c45.y * bflo(w1.y)
            + c67.x * bflo(w1.z) + c67.y * bflo(w1.w);
        z1 += c01.x * bfhi(w0.x) + c01.y * bfhi(w0.y)
            + c23.x * bfhi(w0.z) + c23.y * bfhi(w0.w)
            + c45.x * bfhi(w1.x) + c45.y * bfhi(w1.y)
            + c67.x * bfhi(w1.z) + c67.y * bfhi(w1.w);
    }
    #pragma unroll
    for (int o = 1; o < 64; o <<= 1) {
        z0 += __shfl_xor(z0, o);
        z1 += __shfl_xor(z1, o);
    }
    z1 = z1 / gmax[0];                                 // = a.(s*deg/gmax)
    float dv = deg[row];
    float si = 1.0f / sqrtf(fmaxf(dv + 1.0f, 1.0f));   // exact f32 recompute
    float h = si * (z0 * W1[lane] + z1 * W1[64 + lane]) + b1[lane];
    h = fmaxf(h, 0.f);
    gT[(size_t)lane * N + row] = f2bf(si * h);
}

// Pass 4a: partial t = A @ g over a K-slab. A fp8 in LDS (exact-converted to
// bf16 in regs via v_perm -- fp8 values are exact in bf16), g bf16 in LDS;
// bf16 MFMA 16x16x32. Grid (N/64, KSPLIT); 4 waves; 24 KB LDS double-buffered.
__global__ __launch_bounds__(256) void k_layer2a(const unsigned char* __restrict__ abf,
        const unsigned short* __restrict__ gT, float* __restrict__ tpart) {
    __shared__ unsigned char  Al[2][64 * 64];    // 4 KB each
    __shared__ unsigned short Bl[2][64 * 64];    // 8 KB each
    int tid = threadIdx.x;
    int wave = tid >> 6, lane = tid & 63;
    int r0 = blockIdx.x * 64;
    int kbase0 = blockIdx.y * KPB;

    int r = lane & 15, q = lane >> 4;

    f32x4 acc0 = {0,0,0,0}, acc1 = {0,0,0,0}, acc2 = {0,0,0,0}, acc3 = {0,0,0,0};

    #define STAGE(buf, kbase)                                                   \
        do {                                                                    \
            {                                                                   \
                int idx = tid;                                                  \
                int srow = idx >> 2, sch = (idx & 3) ^ (srow & 3);              \
                glds16(abf + (size_t)(r0 + srow) * N + (kbase) + sch * 16,      \
                       &Al[buf][idx * 16]);                                     \
            }                                                                   \
            _Pragma("unroll")                                                   \
            for (int i = 0; i < 2; ++i) {                                       \
                int idx = i * 256 + tid;                                        \
                int srow = idx >> 3, sch = (idx & 7) ^ (srow & 7);              \
                glds16(gT + (size_t)srow * N + (kbase) + sch * 8,               \
                       &Bl[buf][idx * 8]);                                      \
            }                                                                   \
        } while (0)

    STAGE(0, kbase0);
    __syncthreads();

    for (int t = 0; t < TILES; ++t) {
        int cur = t & 1;
        if (t + 1 < TILES) STAGE(cur ^ 1, kbase0 + (t + 1) * BK);
        int arow = wave * 16 + r;
        #pragma unroll
        for (int ks = 0; ks < 2; ++ks) {            // 2 K-steps of 32 per tile
            int acho = (((ks * 2 + (q >> 1)) ^ (arow & 3)) * 16) + (q & 1) * 8;
            uint2 a8 = *(const uint2*)&Al[cur][arow * 64 + acho];
            f32x2 c01 = __builtin_amdgcn_cvt_pk_f32_fp8((int)a8.x, false);
            f32x2 c23 = __builtin_amdgcn_cvt_pk_f32_fp8((int)a8.x, true);
            f32x2 c45 = __builtin_amdgcn_cvt_pk_f32_fp8((int)a8.y, false);
            f32x2 c67 = __builtin_amdgcn_cvt_pk_f32_fp8((int)a8.y, true);
            union { unsigned u[4]; sh8 v; } af;     // fp8 ⊂ bf16: exact repack
            af.u[0] = __builtin_amdgcn_perm(fbits(c01.y), fbits(c01.x), 0x07060302);
            af.u[1] = __builtin_amdgcn_perm(fbits(c23.y), fbits(c23.x), 0x07060302);
            af.u[2] = __builtin_amdgcn_perm(fbits(c45.y), fbits(c45.x), 0x07060302);
            af.u[3] = __builtin_amdgcn_perm(fbits(c67.y), fbits(c67.x), 0x07060302);
            int chb = ((ks * 4 + q) ^ (r & 7)) * 8;
            sh8 b0 = *(const sh8*)&Bl[cur][(r     ) * 64 + chb];
            sh8 b1 = *(const sh8*)&Bl[cur][(r + 16) * 64 + chb];
            sh8 b2v = *(const sh8*)&Bl[cur][(r + 32) * 64 + chb];
            sh8 b3 = *(const sh8*)&Bl[cur][(r + 48) * 64 + chb];
            acc0 = __builtin_amdgcn_mfma_f32_16x16x32_bf16(af.v, b0,  acc0, 0, 0, 0);
            acc1 = __builtin_amdgcn_mfma_f32_16x16x32_bf16(af.v, b1,  acc1, 0, 0, 0);
            acc2 = __builtin_amdgcn_mfma_f32_16x16x32_bf16(af.v, b2v, acc2, 0, 0, 0);
            acc3 = __builtin_amdgcn_mfma_f32_16x16x32_bf16(af.v, b3,  acc3, 0, 0, 0);
        }
        __syncthreads();   // drains vmcnt(0): next-tile stage has landed
    }
    #undef STAGE

    // C/D layout (m89-verified): col = lane&15, row = (lane>>4)*4 + reg
    float* tp = tpart + (size_t)blockIdx.y * N * 64;
    int growb = r0 + wave * 16 + q * 4;
    #pragma unroll
    for (int rr = 0; rr < 4; ++rr) {
        tp[(size_t)(growb + rr) * 64 + r     ] = acc0[rr];
        tp[(size_t)(growb + rr) * 64 + r + 16] = acc1[rr];
        tp[(size_t)(growb + rr) * 64 + r + 32] = acc2[rr];
        tp[(size_t)(growb + rr) * 64 + r + 48] = acc3[rr];
    }
}

// Pass 4b: t = sum of KSPLIT partials; out = s .* (t @ W2) + b2.
__global__ __launch_bounds__(256) void k_layer2b(const float* __restrict__ tpart,
        const float* __restrict__ deg, const float* __restrict__ W2,
        const float* __restrict__ b2, float* __restrict__ out) {
    __shared__ float ts[4][64];
    int tid = threadIdx.x;
    int r0 = blockIdx.x * 4;
    int rg = tid >> 6, c = tid & 63;
    float v = 0.f;
    #pragma unroll
    for (int kb = 0; kb < KSPLIT; ++kb)
        v += tpart[(size_t)kb * N * 64 + (size_t)(r0 + rg) * 64 + c];
    ts[rg][c] = v;
    __syncthreads();
    float acc = 0.f;
    #pragma unroll 8
    for (int cc = 0; cc < 64; ++cc)
        acc += ts[rg][cc] * W2[cc * 64 + c];
    int row = r0 + rg;
    float dv = deg[row];
    float si = 1.0f / sqrtf(fmaxf(dv + 1.0f, 1.0f));
    out[(size_t)row * 64 + c] = si * acc + b2[c];
}

extern "C" void kernel_launch(void* const* d_in, const int* in_sizes, int n_in,
                              void* d_out, int out_size, void* d_ws, size_t ws_size,
                              hipStream_t stream) {
    const float* adj = (const float*)d_in[0];
    const float* W1  = (const float*)d_in[1];
    const float* b1  = (const float*)d_in[2];
    const float* W2  = (const float*)d_in[3];
    const float* b2  = (const float*)d_in[4];
    float* out = (float*)d_out;

    char* ws = (char*)d_ws;
    unsigned char*  abf = (unsigned char*)ws;                               // 64 MB
    unsigned short* gT  = (unsigned short*)(ws + (size_t)N * N);            // 1 MB
    float* tpart = (float*)(ws + (size_t)N * N + (size_t)64 * N * 2);       // 16 MB
    float* deg = tpart + (size_t)KSPLIT * N * 64;                           // 32 KB
    unsigned* yb = (unsigned*)(deg + N);                                    // 32 KB
    float* gmax = (float*)(yb + N);                                         // 4 B

    hipLaunchKernelGGL(k_deg_conv, dim3(N),      dim3(256),  0, stream, adj, abf, deg, yb);
    hipLaunchKernelGGL(k_gmax,     dim3(1),      dim3(1024), 0, stream, deg, gmax);
    hipLaunchKernelGGL(k_layer1,   dim3(N / 4),  dim3(256),  0, stream,
                       abf, yb, deg, gmax, W1, b1, gT);
    hipLaunchKernelGGL(k_layer2a,  dim3(N / 64, KSPLIT), dim3(256), 0, stream, abf, gT, tpart);
    hipLaunchKernelGGL(k_layer2b,  dim3(N / 4),  dim3(256),  0, stream, tpart, deg, W2, b2, out);
}

// Round 17
// 111.144 us; speedup vs baseline: 3.8412x; 1.0276x over previous
//
#include <hip/hip_runtime.h>
#include <stdint.h>

#define N 8192
#define KSPLIT 8               // K-slabs for k_layer2a
#define BK 64                  // K elems per LDS tile
#define KPB (N / KSPLIT)       // 1024 K per block
#define TILES (KPB / BK)       // 16 tiles per block

typedef __attribute__((ext_vector_type(8))) short sh8;
typedef __attribute__((ext_vector_type(4))) float f32x4;
typedef __attribute__((ext_vector_type(2))) float f32x2;
typedef __attribute__((ext_vector_type(2))) __fp16 h16x2;   // cvt_pkrtz's type

static __device__ __forceinline__ unsigned short f2bf(float f) {
    union { float f; unsigned u; } v; v.f = f;
    unsigned r = v.u + 0x7FFF + ((v.u >> 16) & 1);   // round-to-nearest-even
    return (unsigned short)(r >> 16);
}

static __device__ __forceinline__ unsigned fbits(float f) {
    union { float f; unsigned u; } v; v.f = f;
    return v.u;
}

static __device__ __forceinline__ void glds16(const void* g, void* l) {
    __builtin_amdgcn_global_load_lds(
        (const __attribute__((address_space(1))) void*)g,
        (__attribute__((address_space(3))) void*)l, 16, 0, 0);
}

// Pass 1: deg[i] = row-sum of adj (exact f32); fp8 e4m3 copy of (adj + I);
// tail writes y0h[row] = f16(s), y1h[row] = f16(s*deg) (per-row, no sync).
// adj streamed NON-TEMPORAL so the fresh abf (64 MB) stays L3-resident.
__global__ __launch_bounds__(256) void k_deg_conv(const float* __restrict__ adj,
        unsigned char* __restrict__ abf, float* __restrict__ deg,
        __fp16* __restrict__ y0h, __fp16* __restrict__ y1h) {
    int row = blockIdx.x;
    const float* arow = adj + (size_t)row * N;
    unsigned* brow = (unsigned*)(abf + (size_t)row * N);
    int t = threadIdx.x;
    float sum = 0.f;
    #pragma unroll
    for (int it = 0; it < N / 1024; ++it) {      // 8 iters of f32x4 per thread
        int j = (it * 256 + t) * 4;
        f32x4 v = __builtin_nontemporal_load((const f32x4*)(arow + j));
        sum += v.x + v.y + v.z + v.w;
        int d = row - j;                          // diag lands here iff d in [0,4)
        float x0 = v.x + ((d == 0) ? 1.f : 0.f);
        float x1 = v.y + ((d == 1) ? 1.f : 0.f);
        float x2 = v.z + ((d == 2) ? 1.f : 0.f);
        float x3 = v.w + ((d == 3) ? 1.f : 0.f);
        unsigned p = __builtin_amdgcn_cvt_pk_fp8_f32(x0, x1, 0, false);
        p = __builtin_amdgcn_cvt_pk_fp8_f32(x2, x3, p, true);
        brow[it * 256 + t] = p;                   // 4 fp8 per u32, coalesced
    }
    __shared__ float red[256];
    red[t] = sum; __syncthreads();
    for (int sz = 128; sz > 0; sz >>= 1) {
        if (t < sz) red[t] += red[t + sz];
        __syncthreads();
    }
    if (t == 0) {
        float tot = red[0];
        deg[row] = tot;
        float si = 1.0f / sqrtf(fmaxf(tot + 1.0f, 1.0f));
        y0h[row] = (__fp16)si;                    // f16 ⊇ y magnitudes; RNE
        y1h[row] = (__fp16)(si * tot);
    }
}

// Pass 2: one wave per row. Per-block gmax recompute from deg (32 KB L2-hot,
// order-invariant fmax -> bit-identical across blocks; replaces the k_gmax
// dispatch). z0 = a.s, z1 = a.(s*deg)/gmax via f16 dot2 (a exact in f16);
// h1 = relu(s_i*(z0*W1[0,c]+z1*W1[1,c]) + b1); gT[c][i] = bf16(s_i*h1).
__global__ __launch_bounds__(256) void k_layer1(const unsigned char* __restrict__ abf,
        const __fp16* __restrict__ y0h, const __fp16* __restrict__ y1h,
        const float* __restrict__ deg, const float* __restrict__ W1,
        const float* __restrict__ b1, unsigned short* __restrict__ gT) {
    int tid = threadIdx.x;
    int wave = tid >> 6, lane = tid & 63;
    int row = blockIdx.x * 4 + wave;
    __shared__ float redw[4];
    // --- gmax prologue ---
    float m = 1.0f;
    #pragma unroll
    for (int i = 0; i < N / 256; ++i) m = fmaxf(m, deg[i * 256 + tid]);
    #pragma unroll
    for (int o = 1; o < 64; o <<= 1) m = fmaxf(m, __shfl_xor(m, o));
    if (lane == 0) redw[wave] = m;
    __syncthreads();
    float gmax = fmaxf(fmaxf(redw[0], redw[1]), fmaxf(redw[2], redw[3]));
    // --- main loop ---
    const unsigned char* arow = abf + (size_t)row * N;
    float z0a = 0.f, z0b = 0.f, z1a = 0.f, z1b = 0.f;
    #pragma unroll 4
    for (int it = 0; it < N / 512; ++it) {   // 16 iters, 8 elems/lane/iter
        int j = it * 512 + lane * 8;
        uint2 a8 = *(const uint2*)(arow + j);
        uint4 p0 = *(const uint4*)(y0h + j);      // 8 f16
        uint4 p1 = *(const uint4*)(y1h + j);
        f32x2 c01 = __builtin_amdgcn_cvt_pk_f32_fp8((int)a8.x, false);
        f32x2 c23 = __builtin_amdgcn_cvt_pk_f32_fp8((int)a8.x, true);
        f32x2 c45 = __builtin_amdgcn_cvt_pk_f32_fp8((int)a8.y, false);
        f32x2 c67 = __builtin_amdgcn_cvt_pk_f32_fp8((int)a8.y, true);
        h16x2 a01 = __builtin_amdgcn_cvt_pkrtz(c01.x, c01.y);  // exact: e4m3 ⊂ f16
        h16x2 a23 = __builtin_amdgcn_cvt_pkrtz(c23.x, c23.y);
        h16x2 a45 = __builtin_amdgcn_cvt_pkrtz(c45.x, c45.y);
        h16x2 a67 = __builtin_amdgcn_cvt_pkrtz(c67.x, c67.y);
        z0a = __builtin_amdgcn_fdot2(a01, *(const h16x2*)&p0.x, z0a, false);
        z0b = __builtin_amdgcn_fdot2(a23, *(const h16x2*)&p0.y, z0b, false);
        z0a = __builtin_amdgcn_fdot2(a45, *(const h16x2*)&p0.z, z0a, false);
        z0b = __builtin_amdgcn_fdot2(a67, *(const h16x2*)&p0.w, z0b, false);
        z1a = __builtin_amdgcn_fdot2(a01, *(const h16x2*)&p1.x, z1a, false);
        z1b = __builtin_amdgcn_fdot2(a23, *(const h16x2*)&p1.y, z1b, false);
        z1a = __builtin_amdgcn_fdot2(a45, *(const h16x2*)&p1.z, z1a, false);
        z1b = __builtin_amdgcn_fdot2(a67, *(const h16x2*)&p1.w, z1b, false);
    }
    float z0 = z0a + z0b, z1 = z1a + z1b;
    #pragma unroll
    for (int o = 1; o < 64; o <<= 1) {
        z0 += __shfl_xor(z0, o);
        z1 += __shfl_xor(z1, o);
    }
    z1 = z1 / gmax;                                    // = a.(s*deg/gmax)
    float dv = deg[row];
    float si = 1.0f / sqrtf(fmaxf(dv + 1.0f, 1.0f));   // exact f32 recompute
    float h = si * (z0 * W1[lane] + z1 * W1[64 + lane]) + b1[lane];
    h = fmaxf(h, 0.f);
    gT[(size_t)lane * N + row] = f2bf(si * h);
}

// Pass 3a: partial t = A @ g over a K-slab. A fp8 in LDS (exact-converted to
// bf16 in regs via v_perm), g bf16 in LDS; bf16 MFMA 16x16x32.
// Grid (N/64, KSPLIT); 4 waves; 24 KB LDS double-buffered.
__global__ __launch_bounds__(256) void k_layer2a(const unsigned char* __restrict__ abf,
        const unsigned short* __restrict__ gT, float* __restrict__ tpart) {
    __shared__ unsigned char  Al[2][64 * 64];    // 4 KB each
    __shared__ unsigned short Bl[2][64 * 64];    // 8 KB each
    int tid = threadIdx.x;
    int wave = tid >> 6, lane = tid & 63;
    int r0 = blockIdx.x * 64;
    int kbase0 = blockIdx.y * KPB;

    int r = lane & 15, q = lane >> 4;

    f32x4 acc0 = {0,0,0,0}, acc1 = {0,0,0,0}, acc2 = {0,0,0,0}, acc3 = {0,0,0,0};

    #define STAGE(buf, kbase)                                                   \
        do {                                                                    \
            {                                                                   \
                int idx = tid;                                                  \
                int srow = idx >> 2, sch = (idx & 3) ^ (srow & 3);              \
                glds16(abf + (size_t)(r0 + srow) * N + (kbase) + sch * 16,      \
                       &Al[buf][idx * 16]);                                     \
            }                                                                   \
            _Pragma("unroll")                                                   \
            for (int i = 0; i < 2; ++i) {                                       \
                int idx = i * 256 + tid;                                        \
                int srow = idx >> 3, sch = (idx & 7) ^ (srow & 7);              \
                glds16(gT + (size_t)srow * N + (kbase) + sch * 8,               \
                       &Bl[buf][idx * 8]);                                      \
            }                                                                   \
        } while (0)

    STAGE(0, kbase0);
    __syncthreads();

    for (int t = 0; t < TILES; ++t) {
        int cur = t & 1;
        if (t + 1 < TILES) STAGE(cur ^ 1, kbase0 + (t + 1) * BK);
        int arow = wave * 16 + r;
        #pragma unroll
        for (int ks = 0; ks < 2; ++ks) {            // 2 K-steps of 32 per tile
            int acho = (((ks * 2 + (q >> 1)) ^ (arow & 3)) * 16) + (q & 1) * 8;
            uint2 a8 = *(const uint2*)&Al[cur][arow * 64 + acho];
            f32x2 c01 = __builtin_amdgcn_cvt_pk_f32_fp8((int)a8.x, false);
            f32x2 c23 = __builtin_amdgcn_cvt_pk_f32_fp8((int)a8.x, true);
            f32x2 c45 = __builtin_amdgcn_cvt_pk_f32_fp8((int)a8.y, false);
            f32x2 c67 = __builtin_amdgcn_cvt_pk_f32_fp8((int)a8.y, true);
            union { unsigned u[4]; sh8 v; } af;     // fp8 ⊂ bf16: exact repack
            af.u[0] = __builtin_amdgcn_perm(fbits(c01.y), fbits(c01.x), 0x07060302);
            af.u[1] = __builtin_amdgcn_perm(fbits(c23.y), fbits(c23.x), 0x07060302);
            af.u[2] = __builtin_amdgcn_perm(fbits(c45.y), fbits(c45.x), 0x07060302);
            af.u[3] = __builtin_amdgcn_perm(fbits(c67.y), fbits(c67.x), 0x07060302);
            int chb = ((ks * 4 + q) ^ (r & 7)) * 8;
            sh8 b0 = *(const sh8*)&Bl[cur][(r     ) * 64 + chb];
            sh8 b1 = *(const sh8*)&Bl[cur][(r + 16) * 64 + chb];
            sh8 b2v = *(const sh8*)&Bl[cur][(r + 32) * 64 + chb];
            sh8 b3 = *(const sh8*)&Bl[cur][(r + 48) * 64 + chb];
            acc0 = __builtin_amdgcn_mfma_f32_16x16x32_bf16(af.v, b0,  acc0, 0, 0, 0);
            acc1 = __builtin_amdgcn_mfma_f32_16x16x32_bf16(af.v, b1,  acc1, 0, 0, 0);
            acc2 = __builtin_amdgcn_mfma_f32_16x16x32_bf16(af.v, b2v, acc2, 0, 0, 0);
            acc3 = __builtin_amdgcn_mfma_f32_16x16x32_bf16(af.v, b3,  acc3, 0, 0, 0);
        }
        __syncthreads();   // drains vmcnt(0): next-tile stage has landed
    }
    #undef STAGE

    // C/D layout (m89-verified): col = lane&15, row = (lane>>4)*4 + reg
    float* tp = tpart + (size_t)blockIdx.y * N * 64;
    int growb = r0 + wave * 16 + q * 4;
    #pragma unroll
    for (int rr = 0; rr < 4; ++rr) {
        tp[(size_t)(growb + rr) * 64 + r     ] = acc0[rr];
        tp[(size_t)(growb + rr) * 64 + r + 16] = acc1[rr];
        tp[(size_t)(growb + rr) * 64 + r + 32] = acc2[rr];
        tp[(size_t)(growb + rr) * 64 + r + 48] = acc3[rr];
    }
}

// Pass 3b: t = sum of KSPLIT partials; out = s .* (t @ W2) + b2.
__global__ __launch_bounds__(256) void k_layer2b(const float* __restrict__ tpart,
        const float* __restrict__ deg, const float* __restrict__ W2,
        const float* __restrict__ b2, float* __restrict__ out) {
    __shared__ float ts[4][64];
    int tid = threadIdx.x;
    int r0 = blockIdx.x * 4;
    int rg = tid >> 6, c = tid & 63;
    float v = 0.f;
    #pragma unroll
    for (int kb = 0; kb < KSPLIT; ++kb)
        v += tpart[(size_t)kb * N * 64 + (size_t)(r0 + rg) * 64 + c];
    ts[rg][c] = v;
    __syncthreads();
    float acc = 0.f;
    #pragma unroll 8
    for (int cc = 0; cc < 64; ++cc)
        acc += ts[rg][cc] * W2[cc * 64 + c];
    int row = r0 + rg;
    float dv = deg[row];
    float si = 1.0f / sqrtf(fmaxf(dv + 1.0f, 1.0f));
    out[(size_t)row * 64 + c] = si * acc + b2[c];
}

extern "C" void kernel_launch(void* const* d_in, const int* in_sizes, int n_in,
                              void* d_out, int out_size, void* d_ws, size_t ws_size,
                              hipStream_t stream) {
    const float* adj = (const float*)d_in[0];
    const float* W1  = (const float*)d_in[1];
    const float* b1  = (const float*)d_in[2];
    const float* W2  = (const float*)d_in[3];
    const float* b2  = (const float*)d_in[4];
    float* out = (float*)d_out;

    char* ws = (char*)d_ws;
    unsigned char*  abf = (unsigned char*)ws;                               // 64 MB
    unsigned short* gT  = (unsigned short*)(ws + (size_t)N * N);            // 1 MB
    float* tpart = (float*)(ws + (size_t)N * N + (size_t)64 * N * 2);       // 16 MB
    float* deg = tpart + (size_t)KSPLIT * N * 64;                           // 32 KB
    __fp16* y0h = (__fp16*)(deg + N);                                       // 16 KB
    __fp16* y1h = y0h + N;                                                  // 16 KB

    hipLaunchKernelGGL(k_deg_conv, dim3(N),      dim3(256),  0, stream,
                       adj, abf, deg, y0h, y1h);
    hipLaunchKernelGGL(k_layer1,   dim3(N / 4),  dim3(256),  0, stream,
                       abf, y0h, y1h, deg, W1, b1, gT);
    hipLaunchKernelGGL(k_layer2a,  dim3(N / 64, KSPLIT), dim3(256), 0, stream, abf, gT, tpart);
    hipLaunchKernelGGL(k_layer2b,  dim3(N / 4),  dim3(256),  0, stream, tpart, deg, W2, b2, out);
}